// Round 21
// baseline (335.633 us; speedup 1.0000x reference)
//
#include <hip/hip_runtime.h>
#include <hip/hip_bf16.h>

// VQ-VAE forward, B=64, F=16.  d_out = float*: decoded 4194304 f32, indices 262144 f32.  ws = 256 MiB.
// R21: decoder res chain (dr1, dr2) -> plain bf16 MFMA (res_mfma_k, K=160 padded, 5 MFMA/tile,
//      reuses R17/R20-validated fragment mapping). vq emits bf16 NCHW q; trans_k transposes to
//      ch-last bf16. Encoder (conv1 hi/lo + conv2 split-MFMA + er1/er2 scalar + vq argmin) untouched
//      -> indices stay exact. ws re-laid across 256 MiB (fill evidence R20), all regions disjoint.
// Lessons: uniform weights -> SGPR (R10); matrix pipe beats the ~20-30% scalar-conv issue wall
//      (R17/R20); small-state or bust (R11-R16); never full-unroll wide vector loads (R7,R18).

#define R8X(M)  M(0) M(1) M(2) M(3) M(4) M(5) M(6) M(7)

typedef __attribute__((ext_vector_type(8))) short          bf16x8;
typedef __attribute__((ext_vector_type(8))) unsigned short u16x8;
typedef __attribute__((ext_vector_type(4))) float          f32x4;

__device__ __forceinline__ unsigned short f2bf(float f) {   // RNE fp32 -> bf16 bits
    unsigned u; __builtin_memcpy(&u, &f, 4);
    unsigned r = u + 0x7FFFu + ((u >> 16) & 1u);
    return (unsigned short)(r >> 16);
}
__device__ __forceinline__ float bf2f(unsigned short h) {
    unsigned u = ((unsigned)h) << 16;
    float f; __builtin_memcpy(&f, &u, 4);
    return f;
}

// ---------------- conv1: 1->16, 256->128 — hi/lo bf16 CHANNEL-LAST planes ----------------
__global__ __launch_bounds__(256) void conv1_k(const float* __restrict__ x, const float* __restrict__ w,
                                               const float* __restrict__ bias,
                                               unsigned short* __restrict__ oh, unsigned short* __restrict__ ol) {
    int idx = blockIdx.x * 256 + threadIdx.x;   // 64*128*128
    int ox = idx & 127;
    int oy = (idx >> 7) & 127;
    int b  = idx >> 14;
    const float* xin = x + (size_t)b * 65536;
    float pv[16];
#pragma unroll
    for (int ky = 0; ky < 4; ++ky) {
        int iy = 2 * oy - 1 + ky;
#pragma unroll
        for (int kx = 0; kx < 4; ++kx) {
            int ix = 2 * ox - 1 + kx;
            pv[ky * 4 + kx] = (iy >= 0 && iy < 256 && ix >= 0 && ix < 256)
                                  ? xin[iy * 256 + ix] : 0.f;
        }
    }
    u16x8 h0, h1, l0, l1;
#pragma unroll
    for (int oc = 0; oc < 16; ++oc) {
        float acc = bias[oc];
#pragma unroll
        for (int k = 0; k < 16; ++k) acc = fmaf(pv[k], w[oc * 16 + k], acc);
        float r = fmaxf(acc, 0.f);
        unsigned short hb = f2bf(r);
        unsigned short lb = f2bf(r - bf2f(hb));
        if (oc < 8) { h0[oc] = hb; l0[oc] = lb; }
        else        { h1[oc - 8] = hb; l1[oc - 8] = lb; }
    }
    u16x8* po = (u16x8*)(oh + (size_t)idx * 16);
    po[0] = h0; po[1] = h1;
    u16x8* pl = (u16x8*)(ol + (size_t)idx * 16);
    pl[0] = l0; pl[1] = l1;
}

// ---------------- conv2 via split-bf16 MFMA (R20-validated): K=256, 3 chains ----------------
__global__ __launch_bounds__(256) void conv2_mfma_k(const unsigned short* __restrict__ fh,
                                                    const unsigned short* __restrict__ fl,
                                                    const float* __restrict__ w, const float* __restrict__ bias,
                                                    float* __restrict__ out) {
    __shared__ unsigned short wsh[16 * 264];
    __shared__ unsigned short wsl[16 * 264];
    for (int i = threadIdx.x; i < 4096; i += 256) {
        int oc = i >> 8, k = i & 255;
        int ic = k & 15, tap = k >> 4;
        float f = w[oc * 256 + ic * 16 + tap];
        unsigned short hb = f2bf(f);
        wsh[oc * 264 + k] = hb;
        wsl[oc * 264 + k] = f2bf(f - bf2f(hb));
    }
    __syncthreads();

    int wid  = threadIdx.x >> 6;
    int lane = threadIdx.x & 63;
    int col = lane & 15;
    int kg  = lane >> 4;
    int ic0 = (kg & 1) * 8;
    float accb = bias[col];
    int gw = blockIdx.x * 4 + wid;

    for (int t = 0; t < 2; ++t) {
        int tile = gw * 2 + t;
        int v0  = (tile & 3) * 16;
        int y   = (tile >> 2) & 63;
        int img = tile >> 8;
        const unsigned short* bh = fh + (size_t)img * 262144;
        const unsigned short* bl = fl + (size_t)img * 262144;
        f32x4 acc = { accb, accb, accb, accb };
#pragma unroll
        for (int m = 0; m < 8; ++m) {
            int tap = 2 * m + (kg >> 1);
            int ty = tap >> 2, tx = tap & 3;
            int jy = 2 * y - 1 + ty;
            int jx = 2 * (v0 + col) - 1 + tx;
            bf16x8 ah = { 0, 0, 0, 0, 0, 0, 0, 0 };
            bf16x8 al = { 0, 0, 0, 0, 0, 0, 0, 0 };
            if (jy >= 0 && jy < 128 && jx >= 0 && jx < 128) {
                size_t off = ((size_t)(jy * 128 + jx)) * 16 + ic0;
                ah = *(const bf16x8*)(bh + off);
                al = *(const bf16x8*)(bl + off);
            }
            bf16x8 wh = *(const bf16x8*)&wsh[col * 264 + m * 32 + kg * 8];
            bf16x8 wl = *(const bf16x8*)&wsl[col * 264 + m * 32 + kg * 8];
            acc = __builtin_amdgcn_mfma_f32_16x16x32_bf16(ah, wh, acc, 0, 0, 0);
            acc = __builtin_amdgcn_mfma_f32_16x16x32_bf16(al, wh, acc, 0, 0, 0);
            acc = __builtin_amdgcn_mfma_f32_16x16x32_bf16(ah, wl, acc, 0, 0, 0);
        }
        float* o = out + (size_t)img * 65536 + col * 4096 + y * 64 + v0;
#pragma unroll
        for (int r = 0; r < 4; ++r) {
            int px = kg * 4 + r;
            o[px] = fmaxf(acc[r], 0.f);
        }
    }
}

// ---------------- residual block (encoder, exact fp32) — oc-split halves, NCHW ----------------
__global__ __launch_bounds__(256) void res_k(const float* __restrict__ in, const float* __restrict__ w,
                                             const float* __restrict__ bias, float* __restrict__ out) {
    int half = blockIdx.x >> 10;
    int idx  = (blockIdx.x & 1023) * 256 + threadIdx.x;   // 64*64*64
    int ox = idx & 63;
    int oy = (idx >> 6) & 63;
    int b  = idx >> 12;
    int ocb = half * 8;
    const float* xin = in + (size_t)b * 65536;
    const float* wb  = w + (size_t)ocb * 144;
#define DECLB(i) float a##i = bias[ocb + i];
    R8X(DECLB)
#undef DECLB
    bool yt = (oy > 0), yb = (oy < 63);
    bool xl = (ox > 0), xr = (ox < 63);
    for (int ic = 0; ic < 16; ++ic) {
        const float* xb = xin + ic * 4096 + (oy - 1) * 64 + (ox - 1);
        float pa0 = (yt && xl) ? xb[0]       : 0.f;
        float pa1 =  yt        ? xb[1]       : 0.f;
        float pa2 = (yt && xr) ? xb[2]       : 0.f;
        float pb0 =  xl        ? xb[64 + 0]  : 0.f;
        float pb1 =              xb[64 + 1];
        float pb2 =  xr        ? xb[64 + 2]  : 0.f;
        float pc0 = (yb && xl) ? xb[128 + 0] : 0.f;
        float pc1 =  yb        ? xb[128 + 1] : 0.f;
        float pc2 = (yb && xr) ? xb[128 + 2] : 0.f;
        const float* wp = wb + ic * 9;
#define FMAR(oc) { const float* q = wp + oc * 144; \
        a##oc = fmaf(pa0, q[0], a##oc); a##oc = fmaf(pa1, q[1], a##oc); a##oc = fmaf(pa2, q[2], a##oc); \
        a##oc = fmaf(pb0, q[3], a##oc); a##oc = fmaf(pb1, q[4], a##oc); a##oc = fmaf(pb2, q[5], a##oc); \
        a##oc = fmaf(pc0, q[6], a##oc); a##oc = fmaf(pc1, q[7], a##oc); a##oc = fmaf(pc2, q[8], a##oc); }
        R8X(FMAR)
#undef FMAR
    }
    float* o        = out + (size_t)b * 65536 + (size_t)ocb * 4096 + oy * 64 + ox;
    const float* rr = xin + (size_t)ocb * 4096 + oy * 64 + ox;
#define RSTO(oc) o[oc * 4096] = rr[oc * 4096] + fmaxf(a##oc, 0.f);
    R8X(RSTO)
#undef RSTO
}

// ---------------- VQ: rows of 16 contiguous floats (raw NCHW flatten), K=64 — bf16 NCHW q out ----------------
__global__ __launch_bounds__(256) void vq_k(const float* __restrict__ h, const float* __restrict__ cb,
                                            unsigned short* __restrict__ q, float* __restrict__ idx_out) {
    __shared__ float cbs[1024];  // 64 x 16
    __shared__ float cn[64];
    for (int i = threadIdx.x; i < 1024; i += 256) cbs[i] = cb[i];
    __syncthreads();
    if (threadIdx.x < 64) {
        float s = 0.f;
#pragma unroll
        for (int d = 0; d < 16; ++d) { float v = cbs[threadIdx.x * 16 + d]; s = fmaf(v, v, s); }
        cn[threadIdx.x] = s;
    }
    __syncthreads();
    int r = blockIdx.x * 256 + threadIdx.x;   // 262144 rows
    float f[16];
    const float4* hp = (const float4*)(h + (size_t)r * 16);
#pragma unroll
    for (int j = 0; j < 4; ++j) {
        float4 v = hp[j];
        f[j * 4 + 0] = v.x; f[j * 4 + 1] = v.y; f[j * 4 + 2] = v.z; f[j * 4 + 3] = v.w;
    }
    float best = 3.4e38f;
    int bi = 0;
    for (int k = 0; k < 64; ++k) {
        float dot = 0.f;
#pragma unroll
        for (int d = 0; d < 16; ++d) dot = fmaf(f[d], cbs[k * 16 + d], dot);
        float dist = cn[k] - 2.f * dot;   // +||f||^2 per-row constant, argmin-invariant
        if (dist < best) { best = dist; bi = k; }
    }
    u16x8 q0, q1;
#pragma unroll
    for (int d = 0; d < 8; ++d) {
        q0[d] = f2bf(cbs[bi * 16 + d]);
        q1[d] = f2bf(cbs[bi * 16 + 8 + d]);
    }
    u16x8* qp = (u16x8*)(q + (size_t)r * 16);
    qp[0] = q0; qp[1] = q1;
    idx_out[r] = (float)bi;
}

// ---------------- transpose: (64,16,64,64) bf16 NCHW -> (64,64,64,16) bf16 ch-last ----------------
__global__ __launch_bounds__(256) void trans_k(const unsigned short* __restrict__ in,
                                               unsigned short* __restrict__ out) {
    __shared__ unsigned short lds[16 * 64];
    int b = blockIdx.x >> 6;
    int y = blockIdx.x & 63;
    int t = threadIdx.x;
    {   // read: c = t>>4, x0 = (t&15)*4 — coalesced 8B/lane
        int c = t >> 4, x0 = (t & 15) * 4;
        const unsigned short* p = in + (((size_t)(b * 16 + c) * 64 + y) << 6) + x0;
#pragma unroll
        for (int j = 0; j < 4; ++j) lds[c * 64 + x0 + j] = p[j];
    }
    __syncthreads();
    {   // write: x = t>>2, c0 = (t&3)*4 — contiguous 8B/lane
        int xx = t >> 2, c0 = (t & 3) * 4;
        unsigned short* p = out + (((size_t)(b * 64 + y) * 64 + xx) << 4) + c0;
#pragma unroll
        for (int j = 0; j < 4; ++j) p[j] = lds[(c0 + j) * 64 + xx];
    }
}

// ---------------- res via plain bf16 MFMA (decoder): K=160 padded (9 taps x 16 ic), 5 MFMA/tile ----------------
// in/out (64,64,64,16) ch-last bf16. out = in + relu(conv3x3(in)). Frag mapping = R17/R20-verified.
__global__ __launch_bounds__(256) void res_mfma_k(const unsigned short* __restrict__ in,
                                                  const float* __restrict__ w, const float* __restrict__ bias,
                                                  unsigned short* __restrict__ outb) {
    int wid  = threadIdx.x >> 6;
    int lane = threadIdx.x & 63;
    int col = lane & 15;                 // A px-row / B oc-col / C oc-col
    int kg  = lane >> 4;
    int ic0 = (kg & 1) * 8;
    int gw = blockIdx.x * 4 + wid;       // 16384 waves = 16384 tiles
    int v0  = (gw & 3) * 16;
    int y   = (gw >> 2) & 63;
    int img = gw >> 8;
    const unsigned short* xi = in + (size_t)img * 65536;

    float accb = bias[col];
    f32x4 acc = { accb, accb, accb, accb };
#pragma unroll
    for (int m = 0; m < 5; ++m) {
        int tap = 2 * m + (kg >> 1);     // 0..9 ; tap 9 = zero pad
        bf16x8 a  = { 0, 0, 0, 0, 0, 0, 0, 0 };
        bf16x8 bw = { 0, 0, 0, 0, 0, 0, 0, 0 };
        if (tap < 9) {
            int ty = tap / 3, tx = tap - ty * 3;
            int jy = y + ty - 1;
            int jx = v0 + col + tx - 1;
            if (jy >= 0 && jy < 64 && jx >= 0 && jx < 64)
                a = *(const bf16x8*)(xi + ((jy * 64 + jx) * 16 + ic0));
#pragma unroll
            for (int j = 0; j < 8; ++j)
                bw[j] = (short)f2bf(w[(col * 16 + ic0 + j) * 9 + tap]);
        }
        acc = __builtin_amdgcn_mfma_f32_16x16x32_bf16(a, bw, acc, 0, 0, 0);
    }
#pragma unroll
    for (int r = 0; r < 4; ++r) {
        int px = v0 + kg * 4 + r;
        size_t ad = (size_t)(y * 64 + px) * 16 + col;
        float vin = bf2f(xi[ad]);
        outb[(size_t)img * 65536 + ad] = f2bf(vin + fmaxf(acc[r], 0.f));
    }
}

// ---------------- tconv1 via MFMA: per parity class GEMM M=262144 N=16 K=64 — bf16 out ----------------
__global__ __launch_bounds__(256) void tconv1_mfma_k(const unsigned short* __restrict__ xb,
                                                     const float* __restrict__ w1, const float* __restrict__ bia,
                                                     unsigned short* __restrict__ outb) {
    int cls = blockIdx.x >> 9;           // 4 classes x 512 blocks
    int bb  = blockIdx.x & 511;
    int DY = cls >> 1, DX = cls & 1;
    int wid  = threadIdx.x >> 6;
    int lane = threadIdx.x & 63;
    int oc = lane & 15;
    int kg = lane >> 4;

    bf16x8 bfr0, bfr1;
    float accb = bia[oc];
#pragma unroll
    for (int m = 0; m < 2; ++m) {
        int tap = 2 * m + (kg >> 1);
        int ty = tap >> 1, tx = tap & 1;
        int koff = (3 - DY - 2 * ty) * 4 + (3 - DX - 2 * tx);
        int ic0 = (kg & 1) * 8;
        bf16x8 t;
#pragma unroll
        for (int j = 0; j < 8; ++j)
            t[j] = (short)f2bf(w1[(ic0 + j) * 256 + oc * 16 + koff]);
        if (m == 0) bfr0 = t; else bfr1 = t;
    }

    int Wc = bb * 4 + wid;
    for (int t = 0; t < 8; ++t) {
        int tile = Wc * 8 + t;
        int v0  = (tile & 3) * 16;
        int u   = (tile >> 2) & 63;
        int img = tile >> 8;
        const unsigned short* xi = xb + (size_t)img * 65536;
        f32x4 acc = { accb, accb, accb, accb };
#pragma unroll
        for (int m = 0; m < 2; ++m) {
            int tap = 2 * m + (kg >> 1);
            int ty = tap >> 1, tx = tap & 1;
            int jy = u + DY - 1 + ty;
            int jx = v0 + oc + DX - 1 + tx;
            bf16x8 a = { 0, 0, 0, 0, 0, 0, 0, 0 };
            if (jy >= 0 && jy < 64 && jx >= 0 && jx < 64) {
                int ic0 = (kg & 1) * 8;
                a = *(const bf16x8*)(xi + ((jy * 64 + jx) * 16 + ic0));
            }
            acc = __builtin_amdgcn_mfma_f32_16x16x32_bf16(a, (m == 0 ? bfr0 : bfr1), acc, 0, 0, 0);
        }
        int my = 2 * u + DY;
#pragma unroll
        for (int r = 0; r < 4; ++r) {
            int pxr = kg * 4 + r;
            int mx  = 2 * (v0 + pxr) + DX;
            outb[(((size_t)img * 16384) + my * 128 + mx) * 16 + oc] = f2bf(fmaxf(acc[r], 0.f));
        }
    }
}

// ---------------- tconv2: per-pixel, 4 parity classes, bf16 ch-last input ----------------
template <int PY, int PX>
__device__ __forceinline__ void tconv2_body(const unsigned short* __restrict__ fb,
                                            const float* __restrict__ w2, float b2s,
                                            float* __restrict__ out, int b, int u, int v) {
    float acc = b2s;
#pragma unroll
    for (int a = 0; a < 2; ++a) {
        int jy = u + PY - 1 + a;
        if (jy < 0 || jy >= 128) continue;
#pragma unroll
        for (int c = 0; c < 2; ++c) {
            int jx = v + PX - 1 + c;
            if (jx < 0 || jx >= 128) continue;
            const int ky = 3 - PY - 2 * a;   // literal
            const int kx = 3 - PX - 2 * c;   // literal
            const unsigned short* px = fb + ((size_t)(jy * 128 + jx) << 4);
            u16x8 h0 = *(const u16x8*)px;
            u16x8 h1 = *(const u16x8*)(px + 8);
#pragma unroll
            for (int ic = 0; ic < 8; ++ic)
                acc = fmaf(bf2f(h0[ic]), w2[ic * 16 + ky * 4 + kx], acc);
#pragma unroll
            for (int ic = 0; ic < 8; ++ic)
                acc = fmaf(bf2f(h1[ic]), w2[(ic + 8) * 16 + ky * 4 + kx], acc);
        }
    }
    int gy = 2 * u + PY, gx = 2 * v + PX;
    out[(size_t)b * 65536 + gy * 256 + gx] = acc;
}

__global__ __launch_bounds__(256) void tconv2_par_k(const unsigned short* __restrict__ f1b,
                                                    const float* __restrict__ w2, const float* __restrict__ b2,
                                                    float* __restrict__ out) {
    int cls = blockIdx.x >> 12;                  // 4 classes x 4096 blocks
    int idx = (blockIdx.x & 4095) * 256 + threadIdx.x;   // 64 img * 128*128
    int v = idx & 127;
    int u = (idx >> 7) & 127;
    int b = idx >> 14;
    const unsigned short* fb = f1b + (size_t)b * 262144;
    float b2s = b2[0];
    if      (cls == 0) tconv2_body<0, 0>(fb, w2, b2s, out, b, u, v);
    else if (cls == 1) tconv2_body<0, 1>(fb, w2, b2s, out, b, u, v);
    else if (cls == 2) tconv2_body<1, 0>(fb, w2, b2s, out, b, u, v);
    else               tconv2_body<1, 1>(fb, w2, b2s, out, b, u, v);
}

extern "C" void kernel_launch(void* const* d_in, const int* in_sizes, int n_in,
                              void* d_out, int out_size, void* d_ws, size_t ws_size,
                              hipStream_t stream) {
    const float* x    = (const float*)d_in[0];
    const float* c1w  = (const float*)d_in[1];
    const float* c1b  = (const float*)d_in[2];
    const float* c2w  = (const float*)d_in[3];
    const float* c2b  = (const float*)d_in[4];
    const float* er1w = (const float*)d_in[5];
    const float* er1b = (const float*)d_in[6];
    const float* er2w = (const float*)d_in[7];
    const float* er2b = (const float*)d_in[8];
    const float* cb   = (const float*)d_in[9];
    const float* dr1w = (const float*)d_in[10];
    const float* dr1b = (const float*)d_in[11];
    const float* dr2w = (const float*)d_in[12];
    const float* dr2b = (const float*)d_in[13];
    const float* t1w  = (const float*)d_in[14];
    const float* t1b  = (const float*)d_in[15];
    const float* t2w  = (const float*)d_in[16];
    const float* t2b  = (const float*)d_in[17];

    char* W = (char*)d_ws;                       // 256 MiB confirmed (R20 fill = 2.685e8 B)
    const size_t MB = 1024 * 1024;
    unsigned short* f1h   = (unsigned short*)(W + 0);          // conv1 hi  (64,128,128,16) bf16, 32 MiB
    unsigned short* f1l   = (unsigned short*)(W + 32 * MB);    // conv1 lo, 32 MiB
    float*          f2c   = (float*)         (W + 64 * MB);    // conv2 out  (64,16,64,64) fp32, 16.8 MB
    float*          fer1  = (float*)         (W + 80 * MB);    // er1 out fp32
    float*          fer2  = (float*)         (W + 96 * MB);    // er2 out fp32 (VQ input)
    unsigned short* qn    = (unsigned short*)(W + 112 * MB);   // quantized bf16 NCHW, 8.4 MB
    unsigned short* qc    = (unsigned short*)(W + 128 * MB);   // quantized bf16 ch-last
    unsigned short* d1o   = (unsigned short*)(W + 144 * MB);   // dr1 out ch-last bf16
    unsigned short* d2o   = (unsigned short*)(W + 160 * MB);   // dr2 out ch-last bf16
    unsigned short* t1o   = (unsigned short*)(W + 176 * MB);   // tconv1 out (64,128,128,16) bf16, 33.5 MB

    float* out     = (float*)d_out;              // decoded: 4,194,304 f32
    float* idx_out = out + 4194304;              // indices: 262,144 f32

    conv1_k      <<<4096,  256, 0, stream>>>(x, c1w, c1b, f1h, f1l);
    conv2_mfma_k <<<2048,  256, 0, stream>>>(f1h, f1l, c2w, c2b, f2c);
    res_k        <<<2048,  256, 0, stream>>>(f2c, er1w, er1b, fer1);   // er1 (exact fp32)
    res_k        <<<2048,  256, 0, stream>>>(fer1, er2w, er2b, fer2);  // er2 (exact fp32)
    vq_k         <<<1024,  256, 0, stream>>>(fer2, cb, qn, idx_out);   // argmin exact; q -> bf16 NCHW
    trans_k      <<<4096,  256, 0, stream>>>(qn, qc);                  // -> ch-last bf16
    res_mfma_k   <<<4096,  256, 0, stream>>>(qc, dr1w, dr1b, d1o);     // dr1 (bf16 MFMA)
    res_mfma_k   <<<4096,  256, 0, stream>>>(d1o, dr2w, dr2b, d2o);    // dr2 (bf16 MFMA)
    tconv1_mfma_k<<<2048,  256, 0, stream>>>(d2o, t1w, t1b, t1o);
    tconv2_par_k <<<16384, 256, 0, stream>>>(t1o, t2w, t2b, out);
}

// Round 22
// 240.422 us; speedup vs baseline: 1.3960x; 1.3960x over previous
//
#include <hip/hip_runtime.h>
#include <hip/hip_bf16.h>

// VQ-VAE forward, B=64, F=16.  d_out = float*: decoded 4194304 f32, indices 262144 f32.  ws = 256 MiB.
// R22: res_mfma_k v2 — B-frags hoisted once per wave (R21 rebuilt them per tile: 40 scattered
//      global loads per 5 MFMAs -> 72us latency-bound). Now tconv1-shaped: 512 blocks, 8 tiles/wave.
//      All other kernels byte-identical to R21 (which was byte-identical to validated R20 encoder).
// Pre-commit: res_mfma >= 40us -> revert dr chain to R20 scalar next round.
// Lessons: uniform weights -> SGPR (R10); matrix pipe beats scalar-conv wall (R17/R20); amortize
//      fragment builds over many tiles (R21->R22); small-state or bust; no full-unroll wide loads.

#define R8X(M)  M(0) M(1) M(2) M(3) M(4) M(5) M(6) M(7)

typedef __attribute__((ext_vector_type(8))) short          bf16x8;
typedef __attribute__((ext_vector_type(8))) unsigned short u16x8;
typedef __attribute__((ext_vector_type(4))) float          f32x4;

__device__ __forceinline__ unsigned short f2bf(float f) {   // RNE fp32 -> bf16 bits
    unsigned u; __builtin_memcpy(&u, &f, 4);
    unsigned r = u + 0x7FFFu + ((u >> 16) & 1u);
    return (unsigned short)(r >> 16);
}
__device__ __forceinline__ float bf2f(unsigned short h) {
    unsigned u = ((unsigned)h) << 16;
    float f; __builtin_memcpy(&f, &u, 4);
    return f;
}

// ---------------- conv1: 1->16, 256->128 — hi/lo bf16 CHANNEL-LAST planes ----------------
__global__ __launch_bounds__(256) void conv1_k(const float* __restrict__ x, const float* __restrict__ w,
                                               const float* __restrict__ bias,
                                               unsigned short* __restrict__ oh, unsigned short* __restrict__ ol) {
    int idx = blockIdx.x * 256 + threadIdx.x;   // 64*128*128
    int ox = idx & 127;
    int oy = (idx >> 7) & 127;
    int b  = idx >> 14;
    const float* xin = x + (size_t)b * 65536;
    float pv[16];
#pragma unroll
    for (int ky = 0; ky < 4; ++ky) {
        int iy = 2 * oy - 1 + ky;
#pragma unroll
        for (int kx = 0; kx < 4; ++kx) {
            int ix = 2 * ox - 1 + kx;
            pv[ky * 4 + kx] = (iy >= 0 && iy < 256 && ix >= 0 && ix < 256)
                                  ? xin[iy * 256 + ix] : 0.f;
        }
    }
    u16x8 h0, h1, l0, l1;
#pragma unroll
    for (int oc = 0; oc < 16; ++oc) {
        float acc = bias[oc];
#pragma unroll
        for (int k = 0; k < 16; ++k) acc = fmaf(pv[k], w[oc * 16 + k], acc);
        float r = fmaxf(acc, 0.f);
        unsigned short hb = f2bf(r);
        unsigned short lb = f2bf(r - bf2f(hb));
        if (oc < 8) { h0[oc] = hb; l0[oc] = lb; }
        else        { h1[oc - 8] = hb; l1[oc - 8] = lb; }
    }
    u16x8* po = (u16x8*)(oh + (size_t)idx * 16);
    po[0] = h0; po[1] = h1;
    u16x8* pl = (u16x8*)(ol + (size_t)idx * 16);
    pl[0] = l0; pl[1] = l1;
}

// ---------------- conv2 via split-bf16 MFMA (R20-validated): K=256, 3 chains ----------------
__global__ __launch_bounds__(256) void conv2_mfma_k(const unsigned short* __restrict__ fh,
                                                    const unsigned short* __restrict__ fl,
                                                    const float* __restrict__ w, const float* __restrict__ bias,
                                                    float* __restrict__ out) {
    __shared__ unsigned short wsh[16 * 264];
    __shared__ unsigned short wsl[16 * 264];
    for (int i = threadIdx.x; i < 4096; i += 256) {
        int oc = i >> 8, k = i & 255;
        int ic = k & 15, tap = k >> 4;
        float f = w[oc * 256 + ic * 16 + tap];
        unsigned short hb = f2bf(f);
        wsh[oc * 264 + k] = hb;
        wsl[oc * 264 + k] = f2bf(f - bf2f(hb));
    }
    __syncthreads();

    int wid  = threadIdx.x >> 6;
    int lane = threadIdx.x & 63;
    int col = lane & 15;
    int kg  = lane >> 4;
    int ic0 = (kg & 1) * 8;
    float accb = bias[col];
    int gw = blockIdx.x * 4 + wid;

    for (int t = 0; t < 2; ++t) {
        int tile = gw * 2 + t;
        int v0  = (tile & 3) * 16;
        int y   = (tile >> 2) & 63;
        int img = tile >> 8;
        const unsigned short* bh = fh + (size_t)img * 262144;
        const unsigned short* bl = fl + (size_t)img * 262144;
        f32x4 acc = { accb, accb, accb, accb };
#pragma unroll
        for (int m = 0; m < 8; ++m) {
            int tap = 2 * m + (kg >> 1);
            int ty = tap >> 2, tx = tap & 3;
            int jy = 2 * y - 1 + ty;
            int jx = 2 * (v0 + col) - 1 + tx;
            bf16x8 ah = { 0, 0, 0, 0, 0, 0, 0, 0 };
            bf16x8 al = { 0, 0, 0, 0, 0, 0, 0, 0 };
            if (jy >= 0 && jy < 128 && jx >= 0 && jx < 128) {
                size_t off = ((size_t)(jy * 128 + jx)) * 16 + ic0;
                ah = *(const bf16x8*)(bh + off);
                al = *(const bf16x8*)(bl + off);
            }
            bf16x8 wh = *(const bf16x8*)&wsh[col * 264 + m * 32 + kg * 8];
            bf16x8 wl = *(const bf16x8*)&wsl[col * 264 + m * 32 + kg * 8];
            acc = __builtin_amdgcn_mfma_f32_16x16x32_bf16(ah, wh, acc, 0, 0, 0);
            acc = __builtin_amdgcn_mfma_f32_16x16x32_bf16(al, wh, acc, 0, 0, 0);
            acc = __builtin_amdgcn_mfma_f32_16x16x32_bf16(ah, wl, acc, 0, 0, 0);
        }
        float* o = out + (size_t)img * 65536 + col * 4096 + y * 64 + v0;
#pragma unroll
        for (int r = 0; r < 4; ++r) {
            int px = kg * 4 + r;
            o[px] = fmaxf(acc[r], 0.f);
        }
    }
}

// ---------------- residual block (encoder, exact fp32) — oc-split halves, NCHW ----------------
__global__ __launch_bounds__(256) void res_k(const float* __restrict__ in, const float* __restrict__ w,
                                             const float* __restrict__ bias, float* __restrict__ out) {
    int half = blockIdx.x >> 10;
    int idx  = (blockIdx.x & 1023) * 256 + threadIdx.x;   // 64*64*64
    int ox = idx & 63;
    int oy = (idx >> 6) & 63;
    int b  = idx >> 12;
    int ocb = half * 8;
    const float* xin = in + (size_t)b * 65536;
    const float* wb  = w + (size_t)ocb * 144;
#define DECLB(i) float a##i = bias[ocb + i];
    R8X(DECLB)
#undef DECLB
    bool yt = (oy > 0), yb = (oy < 63);
    bool xl = (ox > 0), xr = (ox < 63);
    for (int ic = 0; ic < 16; ++ic) {
        const float* xb = xin + ic * 4096 + (oy - 1) * 64 + (ox - 1);
        float pa0 = (yt && xl) ? xb[0]       : 0.f;
        float pa1 =  yt        ? xb[1]       : 0.f;
        float pa2 = (yt && xr) ? xb[2]       : 0.f;
        float pb0 =  xl        ? xb[64 + 0]  : 0.f;
        float pb1 =              xb[64 + 1];
        float pb2 =  xr        ? xb[64 + 2]  : 0.f;
        float pc0 = (yb && xl) ? xb[128 + 0] : 0.f;
        float pc1 =  yb        ? xb[128 + 1] : 0.f;
        float pc2 = (yb && xr) ? xb[128 + 2] : 0.f;
        const float* wp = wb + ic * 9;
#define FMAR(oc) { const float* q = wp + oc * 144; \
        a##oc = fmaf(pa0, q[0], a##oc); a##oc = fmaf(pa1, q[1], a##oc); a##oc = fmaf(pa2, q[2], a##oc); \
        a##oc = fmaf(pb0, q[3], a##oc); a##oc = fmaf(pb1, q[4], a##oc); a##oc = fmaf(pb2, q[5], a##oc); \
        a##oc = fmaf(pc0, q[6], a##oc); a##oc = fmaf(pc1, q[7], a##oc); a##oc = fmaf(pc2, q[8], a##oc); }
        R8X(FMAR)
#undef FMAR
    }
    float* o        = out + (size_t)b * 65536 + (size_t)ocb * 4096 + oy * 64 + ox;
    const float* rr = xin + (size_t)ocb * 4096 + oy * 64 + ox;
#define RSTO(oc) o[oc * 4096] = rr[oc * 4096] + fmaxf(a##oc, 0.f);
    R8X(RSTO)
#undef RSTO
}

// ---------------- VQ: rows of 16 contiguous floats, K=64 — bf16 NCHW q out ----------------
__global__ __launch_bounds__(256) void vq_k(const float* __restrict__ h, const float* __restrict__ cb,
                                            unsigned short* __restrict__ q, float* __restrict__ idx_out) {
    __shared__ float cbs[1024];  // 64 x 16
    __shared__ float cn[64];
    for (int i = threadIdx.x; i < 1024; i += 256) cbs[i] = cb[i];
    __syncthreads();
    if (threadIdx.x < 64) {
        float s = 0.f;
#pragma unroll
        for (int d = 0; d < 16; ++d) { float v = cbs[threadIdx.x * 16 + d]; s = fmaf(v, v, s); }
        cn[threadIdx.x] = s;
    }
    __syncthreads();
    int r = blockIdx.x * 256 + threadIdx.x;   // 262144 rows
    float f[16];
    const float4* hp = (const float4*)(h + (size_t)r * 16);
#pragma unroll
    for (int j = 0; j < 4; ++j) {
        float4 v = hp[j];
        f[j * 4 + 0] = v.x; f[j * 4 + 1] = v.y; f[j * 4 + 2] = v.z; f[j * 4 + 3] = v.w;
    }
    float best = 3.4e38f;
    int bi = 0;
    for (int k = 0; k < 64; ++k) {
        float dot = 0.f;
#pragma unroll
        for (int d = 0; d < 16; ++d) dot = fmaf(f[d], cbs[k * 16 + d], dot);
        float dist = cn[k] - 2.f * dot;   // +||f||^2 per-row constant, argmin-invariant
        if (dist < best) { best = dist; bi = k; }
    }
    u16x8 q0, q1;
#pragma unroll
    for (int d = 0; d < 8; ++d) {
        q0[d] = f2bf(cbs[bi * 16 + d]);
        q1[d] = f2bf(cbs[bi * 16 + 8 + d]);
    }
    u16x8* qp = (u16x8*)(q + (size_t)r * 16);
    qp[0] = q0; qp[1] = q1;
    idx_out[r] = (float)bi;
}

// ---------------- transpose: (64,16,64,64) bf16 NCHW -> (64,64,64,16) bf16 ch-last ----------------
__global__ __launch_bounds__(256) void trans_k(const unsigned short* __restrict__ in,
                                               unsigned short* __restrict__ out) {
    __shared__ unsigned short lds[16 * 64];
    int b = blockIdx.x >> 6;
    int y = blockIdx.x & 63;
    int t = threadIdx.x;
    {
        int c = t >> 4, x0 = (t & 15) * 4;
        const unsigned short* p = in + (((size_t)(b * 16 + c) * 64 + y) << 6) + x0;
#pragma unroll
        for (int j = 0; j < 4; ++j) lds[c * 64 + x0 + j] = p[j];
    }
    __syncthreads();
    {
        int xx = t >> 2, c0 = (t & 3) * 4;
        unsigned short* p = out + (((size_t)(b * 64 + y) * 64 + xx) << 4) + c0;
#pragma unroll
        for (int j = 0; j < 4; ++j) p[j] = lds[(c0 + j) * 64 + xx];
    }
}

// ---------------- res via bf16 MFMA v2 (decoder): B-frags hoisted, 8 tiles/wave ----------------
// in/out (64,64,64,16) ch-last bf16. out = in + relu(conv3x3(in)). K=160 padded (taps 0..8 + zero).
__global__ __launch_bounds__(256) void res_mfma_k(const unsigned short* __restrict__ in,
                                                  const float* __restrict__ w, const float* __restrict__ bias,
                                                  unsigned short* __restrict__ outb) {
    int wid  = threadIdx.x >> 6;
    int lane = threadIdx.x & 63;
    int col = lane & 15;                 // A px-row / B oc-col / C oc-col
    int kg  = lane >> 4;
    int ic0 = (kg & 1) * 8;

    // B-frags once per wave: bw[m], tap = 2m + (kg>>1), taps 0..8 real, 9 = zero
    bf16x8 bw[5];
#pragma unroll
    for (int m = 0; m < 5; ++m) {
        int tap = 2 * m + (kg >> 1);
        bf16x8 t = { 0, 0, 0, 0, 0, 0, 0, 0 };
        if (tap < 9) {
#pragma unroll
            for (int j = 0; j < 8; ++j)
                t[j] = (short)f2bf(w[(col * 16 + ic0 + j) * 9 + tap]);
        }
        bw[m] = t;
    }
    float accb = bias[col];

    int gw = blockIdx.x * 4 + wid;       // 2048 waves x 8 tiles = 16384 tiles
    for (int t = 0; t < 8; ++t) {
        int tile = gw * 8 + t;           // img(64) x y(64) x v0(4)
        int v0  = (tile & 3) * 16;
        int y   = (tile >> 2) & 63;
        int img = tile >> 8;
        const unsigned short* xi = in + (size_t)img * 65536;
        f32x4 acc = { accb, accb, accb, accb };
#pragma unroll
        for (int m = 0; m < 5; ++m) {
            int tap = 2 * m + (kg >> 1);
            bf16x8 a = { 0, 0, 0, 0, 0, 0, 0, 0 };
            if (tap < 9) {
                int ty = tap / 3, tx = tap - ty * 3;
                int jy = y + ty - 1;
                int jx = v0 + col + tx - 1;
                if (jy >= 0 && jy < 64 && jx >= 0 && jx < 64)
                    a = *(const bf16x8*)(xi + ((jy * 64 + jx) * 16 + ic0));
            }
            acc = __builtin_amdgcn_mfma_f32_16x16x32_bf16(a, bw[m], acc, 0, 0, 0);
        }
#pragma unroll
        for (int r = 0; r < 4; ++r) {
            int px = v0 + kg * 4 + r;
            size_t ad = (size_t)(y * 64 + px) * 16 + col;
            float vin = bf2f(xi[ad]);
            outb[(size_t)img * 65536 + ad] = f2bf(vin + fmaxf(acc[r], 0.f));
        }
    }
}

// ---------------- tconv1 via MFMA: per parity class GEMM — bf16 out ----------------
__global__ __launch_bounds__(256) void tconv1_mfma_k(const unsigned short* __restrict__ xb,
                                                     const float* __restrict__ w1, const float* __restrict__ bia,
                                                     unsigned short* __restrict__ outb) {
    int cls = blockIdx.x >> 9;           // 4 classes x 512 blocks
    int bb  = blockIdx.x & 511;
    int DY = cls >> 1, DX = cls & 1;
    int wid  = threadIdx.x >> 6;
    int lane = threadIdx.x & 63;
    int oc = lane & 15;
    int kg = lane >> 4;

    bf16x8 bfr0, bfr1;
    float accb = bia[oc];
#pragma unroll
    for (int m = 0; m < 2; ++m) {
        int tap = 2 * m + (kg >> 1);
        int ty = tap >> 1, tx = tap & 1;
        int koff = (3 - DY - 2 * ty) * 4 + (3 - DX - 2 * tx);
        int ic0 = (kg & 1) * 8;
        bf16x8 t;
#pragma unroll
        for (int j = 0; j < 8; ++j)
            t[j] = (short)f2bf(w1[(ic0 + j) * 256 + oc * 16 + koff]);
        if (m == 0) bfr0 = t; else bfr1 = t;
    }

    int Wc = bb * 4 + wid;
    for (int t = 0; t < 8; ++t) {
        int tile = Wc * 8 + t;
        int v0  = (tile & 3) * 16;
        int u   = (tile >> 2) & 63;
        int img = tile >> 8;
        const unsigned short* xi = xb + (size_t)img * 65536;
        f32x4 acc = { accb, accb, accb, accb };
#pragma unroll
        for (int m = 0; m < 2; ++m) {
            int tap = 2 * m + (kg >> 1);
            int ty = tap >> 1, tx = tap & 1;
            int jy = u + DY - 1 + ty;
            int jx = v0 + oc + DX - 1 + tx;
            bf16x8 a = { 0, 0, 0, 0, 0, 0, 0, 0 };
            if (jy >= 0 && jy < 64 && jx >= 0 && jx < 64) {
                int ic0 = (kg & 1) * 8;
                a = *(const bf16x8*)(xi + ((jy * 64 + jx) * 16 + ic0));
            }
            acc = __builtin_amdgcn_mfma_f32_16x16x32_bf16(a, (m == 0 ? bfr0 : bfr1), acc, 0, 0, 0);
        }
        int my = 2 * u + DY;
#pragma unroll
        for (int r = 0; r < 4; ++r) {
            int pxr = kg * 4 + r;
            int mx  = 2 * (v0 + pxr) + DX;
            outb[(((size_t)img * 16384) + my * 128 + mx) * 16 + oc] = f2bf(fmaxf(acc[r], 0.f));
        }
    }
}

// ---------------- tconv2: per-pixel, 4 parity classes, bf16 ch-last input ----------------
template <int PY, int PX>
__device__ __forceinline__ void tconv2_body(const unsigned short* __restrict__ fb,
                                            const float* __restrict__ w2, float b2s,
                                            float* __restrict__ out, int b, int u, int v) {
    float acc = b2s;
#pragma unroll
    for (int a = 0; a < 2; ++a) {
        int jy = u + PY - 1 + a;
        if (jy < 0 || jy >= 128) continue;
#pragma unroll
        for (int c = 0; c < 2; ++c) {
            int jx = v + PX - 1 + c;
            if (jx < 0 || jx >= 128) continue;
            const int ky = 3 - PY - 2 * a;   // literal
            const int kx = 3 - PX - 2 * c;   // literal
            const unsigned short* px = fb + ((size_t)(jy * 128 + jx) << 4);
            u16x8 h0 = *(const u16x8*)px;
            u16x8 h1 = *(const u16x8*)(px + 8);
#pragma unroll
            for (int ic = 0; ic < 8; ++ic)
                acc = fmaf(bf2f(h0[ic]), w2[ic * 16 + ky * 4 + kx], acc);
#pragma unroll
            for (int ic = 0; ic < 8; ++ic)
                acc = fmaf(bf2f(h1[ic]), w2[(ic + 8) * 16 + ky * 4 + kx], acc);
        }
    }
    int gy = 2 * u + PY, gx = 2 * v + PX;
    out[(size_t)b * 65536 + gy * 256 + gx] = acc;
}

__global__ __launch_bounds__(256) void tconv2_par_k(const unsigned short* __restrict__ f1b,
                                                    const float* __restrict__ w2, const float* __restrict__ b2,
                                                    float* __restrict__ out) {
    int cls = blockIdx.x >> 12;                  // 4 classes x 4096 blocks
    int idx = (blockIdx.x & 4095) * 256 + threadIdx.x;   // 64 img * 128*128
    int v = idx & 127;
    int u = (idx >> 7) & 127;
    int b = idx >> 14;
    const unsigned short* fb = f1b + (size_t)b * 262144;
    float b2s = b2[0];
    if      (cls == 0) tconv2_body<0, 0>(fb, w2, b2s, out, b, u, v);
    else if (cls == 1) tconv2_body<0, 1>(fb, w2, b2s, out, b, u, v);
    else if (cls == 2) tconv2_body<1, 0>(fb, w2, b2s, out, b, u, v);
    else               tconv2_body<1, 1>(fb, w2, b2s, out, b, u, v);
}

extern "C" void kernel_launch(void* const* d_in, const int* in_sizes, int n_in,
                              void* d_out, int out_size, void* d_ws, size_t ws_size,
                              hipStream_t stream) {
    const float* x    = (const float*)d_in[0];
    const float* c1w  = (const float*)d_in[1];
    const float* c1b  = (const float*)d_in[2];
    const float* c2w  = (const float*)d_in[3];
    const float* c2b  = (const float*)d_in[4];
    const float* er1w = (const float*)d_in[5];
    const float* er1b = (const float*)d_in[6];
    const float* er2w = (const float*)d_in[7];
    const float* er2b = (const float*)d_in[8];
    const float* cb   = (const float*)d_in[9];
    const float* dr1w = (const float*)d_in[10];
    const float* dr1b = (const float*)d_in[11];
    const float* dr2w = (const float*)d_in[12];
    const float* dr2b = (const float*)d_in[13];
    const float* t1w  = (const float*)d_in[14];
    const float* t1b  = (const float*)d_in[15];
    const float* t2w  = (const float*)d_in[16];
    const float* t2b  = (const float*)d_in[17];

    char* W = (char*)d_ws;                       // 256 MiB (R20 fill evidence)
    const size_t MB = 1024 * 1024;
    unsigned short* f1h   = (unsigned short*)(W + 0);          // conv1 hi  (64,128,128,16) bf16
    unsigned short* f1l   = (unsigned short*)(W + 32 * MB);    // conv1 lo
    float*          f2c   = (float*)         (W + 64 * MB);    // conv2 out  (64,16,64,64) fp32
    float*          fer1  = (float*)         (W + 80 * MB);    // er1 out fp32
    float*          fer2  = (float*)         (W + 96 * MB);    // er2 out fp32 (VQ input)
    unsigned short* qn    = (unsigned short*)(W + 112 * MB);   // quantized bf16 NCHW
    unsigned short* qc    = (unsigned short*)(W + 128 * MB);   // quantized bf16 ch-last
    unsigned short* d1o   = (unsigned short*)(W + 144 * MB);   // dr1 out ch-last bf16
    unsigned short* d2o   = (unsigned short*)(W + 160 * MB);   // dr2 out ch-last bf16
    unsigned short* t1o   = (unsigned short*)(W + 176 * MB);   // tconv1 out (64,128,128,16) bf16

    float* out     = (float*)d_out;              // decoded: 4,194,304 f32
    float* idx_out = out + 4194304;              // indices: 262,144 f32

    conv1_k      <<<4096,  256, 0, stream>>>(x, c1w, c1b, f1h, f1l);
    conv2_mfma_k <<<2048,  256, 0, stream>>>(f1h, f1l, c2w, c2b, f2c);
    res_k        <<<2048,  256, 0, stream>>>(f2c, er1w, er1b, fer1);   // er1 (exact fp32)
    res_k        <<<2048,  256, 0, stream>>>(fer1, er2w, er2b, fer2);  // er2 (exact fp32)
    vq_k         <<<1024,  256, 0, stream>>>(fer2, cb, qn, idx_out);   // argmin exact
    trans_k      <<<4096,  256, 0, stream>>>(qn, qc);                  // -> ch-last bf16
    res_mfma_k   <<< 512,  256, 0, stream>>>(qc, dr1w, dr1b, d1o);     // dr1 (bf16 MFMA v2)
    res_mfma_k   <<< 512,  256, 0, stream>>>(d1o, dr2w, dr2b, d2o);    // dr2 (bf16 MFMA v2)
    tconv1_mfma_k<<<2048,  256, 0, stream>>>(d2o, t1w, t1b, t1o);
    tconv2_par_k <<<16384, 256, 0, stream>>>(t1o, t2w, t2b, out);
}

// Round 23
// 223.373 us; speedup vs baseline: 1.5026x; 1.0763x over previous
//
#include <hip/hip_runtime.h>
#include <hip/hip_bf16.h>

// VQ-VAE forward, B=64, F=16.  d_out = float*: decoded 4194304 f32, indices 262144 f32.  ws = 256 MiB.
// R23: tconv2 -> 2x2-quad kernel (merges R19's 4 parity classes): 3x3 shared input neighborhood
//      (reads /4), contiguous float2 row-pair stores (writes /2). Weight (dy,ky)/(dx,kx) lists are
//      constexpr per (ry,rx) -> uniform -> SGPR. Everything else byte-identical to R22 (240.4us).
// Ledger (R22): tconv2 39.4 | conv2m ~40 | conv1 ~30 | er1/er2 ~21ea | res_mfma ~13ea | vq ~12 |
//      tconv1m ~12 | trans ~4.
// Lessons: uniform weights -> SGPR (R10); matrix pipe beats scalar-conv wall (R17/R20); hoist
//      fragment builds (R22); merge parity classes to share reads (R23); small-state or bust.

#define R8X(M)  M(0) M(1) M(2) M(3) M(4) M(5) M(6) M(7)

typedef __attribute__((ext_vector_type(8))) short          bf16x8;
typedef __attribute__((ext_vector_type(8))) unsigned short u16x8;
typedef __attribute__((ext_vector_type(4))) float          f32x4;

__device__ __forceinline__ unsigned short f2bf(float f) {   // RNE fp32 -> bf16 bits
    unsigned u; __builtin_memcpy(&u, &f, 4);
    unsigned r = u + 0x7FFFu + ((u >> 16) & 1u);
    return (unsigned short)(r >> 16);
}
__device__ __forceinline__ float bf2f(unsigned short h) {
    unsigned u = ((unsigned)h) << 16;
    float f; __builtin_memcpy(&f, &u, 4);
    return f;
}

// ---------------- conv1: 1->16, 256->128 — hi/lo bf16 CHANNEL-LAST planes ----------------
__global__ __launch_bounds__(256) void conv1_k(const float* __restrict__ x, const float* __restrict__ w,
                                               const float* __restrict__ bias,
                                               unsigned short* __restrict__ oh, unsigned short* __restrict__ ol) {
    int idx = blockIdx.x * 256 + threadIdx.x;   // 64*128*128
    int ox = idx & 127;
    int oy = (idx >> 7) & 127;
    int b  = idx >> 14;
    const float* xin = x + (size_t)b * 65536;
    float pv[16];
#pragma unroll
    for (int ky = 0; ky < 4; ++ky) {
        int iy = 2 * oy - 1 + ky;
#pragma unroll
        for (int kx = 0; kx < 4; ++kx) {
            int ix = 2 * ox - 1 + kx;
            pv[ky * 4 + kx] = (iy >= 0 && iy < 256 && ix >= 0 && ix < 256)
                                  ? xin[iy * 256 + ix] : 0.f;
        }
    }
    u16x8 h0, h1, l0, l1;
#pragma unroll
    for (int oc = 0; oc < 16; ++oc) {
        float acc = bias[oc];
#pragma unroll
        for (int k = 0; k < 16; ++k) acc = fmaf(pv[k], w[oc * 16 + k], acc);
        float r = fmaxf(acc, 0.f);
        unsigned short hb = f2bf(r);
        unsigned short lb = f2bf(r - bf2f(hb));
        if (oc < 8) { h0[oc] = hb; l0[oc] = lb; }
        else        { h1[oc - 8] = hb; l1[oc - 8] = lb; }
    }
    u16x8* po = (u16x8*)(oh + (size_t)idx * 16);
    po[0] = h0; po[1] = h1;
    u16x8* pl = (u16x8*)(ol + (size_t)idx * 16);
    pl[0] = l0; pl[1] = l1;
}

// ---------------- conv2 via split-bf16 MFMA (R20-validated): K=256, 3 chains ----------------
__global__ __launch_bounds__(256) void conv2_mfma_k(const unsigned short* __restrict__ fh,
                                                    const unsigned short* __restrict__ fl,
                                                    const float* __restrict__ w, const float* __restrict__ bias,
                                                    float* __restrict__ out) {
    __shared__ unsigned short wsh[16 * 264];
    __shared__ unsigned short wsl[16 * 264];
    for (int i = threadIdx.x; i < 4096; i += 256) {
        int oc = i >> 8, k = i & 255;
        int ic = k & 15, tap = k >> 4;
        float f = w[oc * 256 + ic * 16 + tap];
        unsigned short hb = f2bf(f);
        wsh[oc * 264 + k] = hb;
        wsl[oc * 264 + k] = f2bf(f - bf2f(hb));
    }
    __syncthreads();

    int wid  = threadIdx.x >> 6;
    int lane = threadIdx.x & 63;
    int col = lane & 15;
    int kg  = lane >> 4;
    int ic0 = (kg & 1) * 8;
    float accb = bias[col];
    int gw = blockIdx.x * 4 + wid;

    for (int t = 0; t < 2; ++t) {
        int tile = gw * 2 + t;
        int v0  = (tile & 3) * 16;
        int y   = (tile >> 2) & 63;
        int img = tile >> 8;
        const unsigned short* bh = fh + (size_t)img * 262144;
        const unsigned short* bl = fl + (size_t)img * 262144;
        f32x4 acc = { accb, accb, accb, accb };
#pragma unroll
        for (int m = 0; m < 8; ++m) {
            int tap = 2 * m + (kg >> 1);
            int ty = tap >> 2, tx = tap & 3;
            int jy = 2 * y - 1 + ty;
            int jx = 2 * (v0 + col) - 1 + tx;
            bf16x8 ah = { 0, 0, 0, 0, 0, 0, 0, 0 };
            bf16x8 al = { 0, 0, 0, 0, 0, 0, 0, 0 };
            if (jy >= 0 && jy < 128 && jx >= 0 && jx < 128) {
                size_t off = ((size_t)(jy * 128 + jx)) * 16 + ic0;
                ah = *(const bf16x8*)(bh + off);
                al = *(const bf16x8*)(bl + off);
            }
            bf16x8 wh = *(const bf16x8*)&wsh[col * 264 + m * 32 + kg * 8];
            bf16x8 wl = *(const bf16x8*)&wsl[col * 264 + m * 32 + kg * 8];
            acc = __builtin_amdgcn_mfma_f32_16x16x32_bf16(ah, wh, acc, 0, 0, 0);
            acc = __builtin_amdgcn_mfma_f32_16x16x32_bf16(al, wh, acc, 0, 0, 0);
            acc = __builtin_amdgcn_mfma_f32_16x16x32_bf16(ah, wl, acc, 0, 0, 0);
        }
        float* o = out + (size_t)img * 65536 + col * 4096 + y * 64 + v0;
#pragma unroll
        for (int r = 0; r < 4; ++r) {
            int px = kg * 4 + r;
            o[px] = fmaxf(acc[r], 0.f);
        }
    }
}

// ---------------- residual block (encoder, exact fp32) — oc-split halves, NCHW ----------------
__global__ __launch_bounds__(256) void res_k(const float* __restrict__ in, const float* __restrict__ w,
                                             const float* __restrict__ bias, float* __restrict__ out) {
    int half = blockIdx.x >> 10;
    int idx  = (blockIdx.x & 1023) * 256 + threadIdx.x;   // 64*64*64
    int ox = idx & 63;
    int oy = (idx >> 6) & 63;
    int b  = idx >> 12;
    int ocb = half * 8;
    const float* xin = in + (size_t)b * 65536;
    const float* wb  = w + (size_t)ocb * 144;
#define DECLB(i) float a##i = bias[ocb + i];
    R8X(DECLB)
#undef DECLB
    bool yt = (oy > 0), yb = (oy < 63);
    bool xl = (ox > 0), xr = (ox < 63);
    for (int ic = 0; ic < 16; ++ic) {
        const float* xb = xin + ic * 4096 + (oy - 1) * 64 + (ox - 1);
        float pa0 = (yt && xl) ? xb[0]       : 0.f;
        float pa1 =  yt        ? xb[1]       : 0.f;
        float pa2 = (yt && xr) ? xb[2]       : 0.f;
        float pb0 =  xl        ? xb[64 + 0]  : 0.f;
        float pb1 =              xb[64 + 1];
        float pb2 =  xr        ? xb[64 + 2]  : 0.f;
        float pc0 = (yb && xl) ? xb[128 + 0] : 0.f;
        float pc1 =  yb        ? xb[128 + 1] : 0.f;
        float pc2 = (yb && xr) ? xb[128 + 2] : 0.f;
        const float* wp = wb + ic * 9;
#define FMAR(oc) { const float* q = wp + oc * 144; \
        a##oc = fmaf(pa0, q[0], a##oc); a##oc = fmaf(pa1, q[1], a##oc); a##oc = fmaf(pa2, q[2], a##oc); \
        a##oc = fmaf(pb0, q[3], a##oc); a##oc = fmaf(pb1, q[4], a##oc); a##oc = fmaf(pb2, q[5], a##oc); \
        a##oc = fmaf(pc0, q[6], a##oc); a##oc = fmaf(pc1, q[7], a##oc); a##oc = fmaf(pc2, q[8], a##oc); }
        R8X(FMAR)
#undef FMAR
    }
    float* o        = out + (size_t)b * 65536 + (size_t)ocb * 4096 + oy * 64 + ox;
    const float* rr = xin + (size_t)ocb * 4096 + oy * 64 + ox;
#define RSTO(oc) o[oc * 4096] = rr[oc * 4096] + fmaxf(a##oc, 0.f);
    R8X(RSTO)
#undef RSTO
}

// ---------------- VQ: rows of 16 contiguous floats, K=64 — bf16 NCHW q out ----------------
__global__ __launch_bounds__(256) void vq_k(const float* __restrict__ h, const float* __restrict__ cb,
                                            unsigned short* __restrict__ q, float* __restrict__ idx_out) {
    __shared__ float cbs[1024];  // 64 x 16
    __shared__ float cn[64];
    for (int i = threadIdx.x; i < 1024; i += 256) cbs[i] = cb[i];
    __syncthreads();
    if (threadIdx.x < 64) {
        float s = 0.f;
#pragma unroll
        for (int d = 0; d < 16; ++d) { float v = cbs[threadIdx.x * 16 + d]; s = fmaf(v, v, s); }
        cn[threadIdx.x] = s;
    }
    __syncthreads();
    int r = blockIdx.x * 256 + threadIdx.x;   // 262144 rows
    float f[16];
    const float4* hp = (const float4*)(h + (size_t)r * 16);
#pragma unroll
    for (int j = 0; j < 4; ++j) {
        float4 v = hp[j];
        f[j * 4 + 0] = v.x; f[j * 4 + 1] = v.y; f[j * 4 + 2] = v.z; f[j * 4 + 3] = v.w;
    }
    float best = 3.4e38f;
    int bi = 0;
    for (int k = 0; k < 64; ++k) {
        float dot = 0.f;
#pragma unroll
        for (int d = 0; d < 16; ++d) dot = fmaf(f[d], cbs[k * 16 + d], dot);
        float dist = cn[k] - 2.f * dot;   // +||f||^2 per-row constant, argmin-invariant
        if (dist < best) { best = dist; bi = k; }
    }
    u16x8 q0, q1;
#pragma unroll
    for (int d = 0; d < 8; ++d) {
        q0[d] = f2bf(cbs[bi * 16 + d]);
        q1[d] = f2bf(cbs[bi * 16 + 8 + d]);
    }
    u16x8* qp = (u16x8*)(q + (size_t)r * 16);
    qp[0] = q0; qp[1] = q1;
    idx_out[r] = (float)bi;
}

// ---------------- transpose: (64,16,64,64) bf16 NCHW -> (64,64,64,16) bf16 ch-last ----------------
__global__ __launch_bounds__(256) void trans_k(const unsigned short* __restrict__ in,
                                               unsigned short* __restrict__ out) {
    __shared__ unsigned short lds[16 * 64];
    int b = blockIdx.x >> 6;
    int y = blockIdx.x & 63;
    int t = threadIdx.x;
    {
        int c = t >> 4, x0 = (t & 15) * 4;
        const unsigned short* p = in + (((size_t)(b * 16 + c) * 64 + y) << 6) + x0;
#pragma unroll
        for (int j = 0; j < 4; ++j) lds[c * 64 + x0 + j] = p[j];
    }
    __syncthreads();
    {
        int xx = t >> 2, c0 = (t & 3) * 4;
        unsigned short* p = out + (((size_t)(b * 64 + y) * 64 + xx) << 4) + c0;
#pragma unroll
        for (int j = 0; j < 4; ++j) p[j] = lds[(c0 + j) * 64 + xx];
    }
}

// ---------------- res via bf16 MFMA v2 (decoder): B-frags hoisted, 8 tiles/wave ----------------
__global__ __launch_bounds__(256) void res_mfma_k(const unsigned short* __restrict__ in,
                                                  const float* __restrict__ w, const float* __restrict__ bias,
                                                  unsigned short* __restrict__ outb) {
    int wid  = threadIdx.x >> 6;
    int lane = threadIdx.x & 63;
    int col = lane & 15;
    int kg  = lane >> 4;
    int ic0 = (kg & 1) * 8;

    bf16x8 bw[5];
#pragma unroll
    for (int m = 0; m < 5; ++m) {
        int tap = 2 * m + (kg >> 1);
        bf16x8 t = { 0, 0, 0, 0, 0, 0, 0, 0 };
        if (tap < 9) {
#pragma unroll
            for (int j = 0; j < 8; ++j)
                t[j] = (short)f2bf(w[(col * 16 + ic0 + j) * 9 + tap]);
        }
        bw[m] = t;
    }
    float accb = bias[col];

    int gw = blockIdx.x * 4 + wid;       // 2048 waves x 8 tiles
    for (int t = 0; t < 8; ++t) {
        int tile = gw * 8 + t;
        int v0  = (tile & 3) * 16;
        int y   = (tile >> 2) & 63;
        int img = tile >> 8;
        const unsigned short* xi = in + (size_t)img * 65536;
        f32x4 acc = { accb, accb, accb, accb };
#pragma unroll
        for (int m = 0; m < 5; ++m) {
            int tap = 2 * m + (kg >> 1);
            bf16x8 a = { 0, 0, 0, 0, 0, 0, 0, 0 };
            if (tap < 9) {
                int ty = tap / 3, tx = tap - ty * 3;
                int jy = y + ty - 1;
                int jx = v0 + col + tx - 1;
                if (jy >= 0 && jy < 64 && jx >= 0 && jx < 64)
                    a = *(const bf16x8*)(xi + ((jy * 64 + jx) * 16 + ic0));
            }
            acc = __builtin_amdgcn_mfma_f32_16x16x32_bf16(a, bw[m], acc, 0, 0, 0);
        }
#pragma unroll
        for (int r = 0; r < 4; ++r) {
            int px = v0 + kg * 4 + r;
            size_t ad = (size_t)(y * 64 + px) * 16 + col;
            float vin = bf2f(xi[ad]);
            outb[(size_t)img * 65536 + ad] = f2bf(vin + fmaxf(acc[r], 0.f));
        }
    }
}

// ---------------- tconv1 via MFMA: per parity class GEMM — bf16 out ----------------
__global__ __launch_bounds__(256) void tconv1_mfma_k(const unsigned short* __restrict__ xb,
                                                     const float* __restrict__ w1, const float* __restrict__ bia,
                                                     unsigned short* __restrict__ outb) {
    int cls = blockIdx.x >> 9;           // 4 classes x 512 blocks
    int bb  = blockIdx.x & 511;
    int DY = cls >> 1, DX = cls & 1;
    int wid  = threadIdx.x >> 6;
    int lane = threadIdx.x & 63;
    int oc = lane & 15;
    int kg = lane >> 4;

    bf16x8 bfr0, bfr1;
    float accb = bia[oc];
#pragma unroll
    for (int m = 0; m < 2; ++m) {
        int tap = 2 * m + (kg >> 1);
        int ty = tap >> 1, tx = tap & 1;
        int koff = (3 - DY - 2 * ty) * 4 + (3 - DX - 2 * tx);
        int ic0 = (kg & 1) * 8;
        bf16x8 t;
#pragma unroll
        for (int j = 0; j < 8; ++j)
            t[j] = (short)f2bf(w1[(ic0 + j) * 256 + oc * 16 + koff]);
        if (m == 0) bfr0 = t; else bfr1 = t;
    }

    int Wc = bb * 4 + wid;
    for (int t = 0; t < 8; ++t) {
        int tile = Wc * 8 + t;
        int v0  = (tile & 3) * 16;
        int u   = (tile >> 2) & 63;
        int img = tile >> 8;
        const unsigned short* xi = xb + (size_t)img * 65536;
        f32x4 acc = { accb, accb, accb, accb };
#pragma unroll
        for (int m = 0; m < 2; ++m) {
            int tap = 2 * m + (kg >> 1);
            int ty = tap >> 1, tx = tap & 1;
            int jy = u + DY - 1 + ty;
            int jx = v0 + oc + DX - 1 + tx;
            bf16x8 a = { 0, 0, 0, 0, 0, 0, 0, 0 };
            if (jy >= 0 && jy < 64 && jx >= 0 && jx < 64) {
                int ic0 = (kg & 1) * 8;
                a = *(const bf16x8*)(xi + ((jy * 64 + jx) * 16 + ic0));
            }
            acc = __builtin_amdgcn_mfma_f32_16x16x32_bf16(a, (m == 0 ? bfr0 : bfr1), acc, 0, 0, 0);
        }
        int my = 2 * u + DY;
#pragma unroll
        for (int r = 0; r < 4; ++r) {
            int pxr = kg * 4 + r;
            int mx  = 2 * (v0 + pxr) + DX;
            outb[(((size_t)img * 16384) + my * 128 + mx) * 16 + oc] = f2bf(fmaxf(acc[r], 0.f));
        }
    }
}

// ---------------- tconv2: 2x2-quad kernel — 3x3 shared neighborhood, contiguous stores ----------------
template <int RY, int RX>
__device__ __forceinline__ void quad_contrib(const unsigned short* __restrict__ px,
                                             const float* __restrict__ w2,
                                             float& a00, float& a01, float& a10, float& a11) {
    constexpr int nY = (RY == 0) ? 2 : 1;
    constexpr int nX = (RX == 0) ? 2 : 1;
    constexpr int dyA[2] = { (RY == 1) ? 1 : 0, 1 };
    constexpr int kyA[2] = { (RY == -1) ? 3 : ((RY == 0) ? 1 : 0), 2 };
    constexpr int dxA[2] = { (RX == 1) ? 1 : 0, 1 };
    constexpr int kxA[2] = { (RX == -1) ? 3 : ((RX == 0) ? 1 : 0), 2 };
    u16x8 h0 = *(const u16x8*)px;
    u16x8 h1 = *(const u16x8*)(px + 8);
#pragma unroll
    for (int iy = 0; iy < nY; ++iy) {
#pragma unroll
        for (int ix = 0; ix < nX; ++ix) {
            const int ky = kyA[iy], kx = kxA[ix];   // compile-time
            float& a = (dyA[iy] == 0) ? ((dxA[ix] == 0) ? a00 : a01)
                                      : ((dxA[ix] == 0) ? a10 : a11);
#pragma unroll
            for (int ic = 0; ic < 8; ++ic)
                a = fmaf(bf2f(h0[ic]), w2[ic * 16 + ky * 4 + kx], a);          // uniform -> SGPR
#pragma unroll
            for (int ic = 0; ic < 8; ++ic)
                a = fmaf(bf2f(h1[ic]), w2[(ic + 8) * 16 + ky * 4 + kx], a);
        }
    }
}

__global__ __launch_bounds__(256) void tconv2_quad_k(const unsigned short* __restrict__ f1b,
                                                     const float* __restrict__ w2, const float* __restrict__ b2,
                                                     float* __restrict__ out) {
    int idx = blockIdx.x * 256 + threadIdx.x;   // 64 img * 128*128 quads
    int v = idx & 127;
    int u = (idx >> 7) & 127;
    int b = idx >> 14;
    const unsigned short* fb = f1b + (size_t)b * 262144;   // (128,128,16) ch-last bf16
    float b2s = b2[0];
    float a00 = b2s, a01 = b2s, a10 = b2s, a11 = b2s;      // [dy][dx]

#define QC(RY, RX) { int jy = u + (RY), jx = v + (RX); \
    if (jy >= 0 && jy < 128 && jx >= 0 && jx < 128) \
        quad_contrib<RY, RX>(fb + ((size_t)(jy * 128 + jx) << 4), w2, a00, a01, a10, a11); }
    QC(-1, -1) QC(-1, 0) QC(-1, 1)
    QC( 0, -1) QC( 0, 0) QC( 0, 1)
    QC( 1, -1) QC( 1, 0) QC( 1, 1)
#undef QC

    float* o = out + (size_t)b * 65536 + (2 * u) * 256 + 2 * v;
    float2 r0; r0.x = a00; r0.y = a01;
    float2 r1; r1.x = a10; r1.y = a11;
    *(float2*)o         = r0;
    *(float2*)(o + 256) = r1;
}

extern "C" void kernel_launch(void* const* d_in, const int* in_sizes, int n_in,
                              void* d_out, int out_size, void* d_ws, size_t ws_size,
                              hipStream_t stream) {
    const float* x    = (const float*)d_in[0];
    const float* c1w  = (const float*)d_in[1];
    const float* c1b  = (const float*)d_in[2];
    const float* c2w  = (const float*)d_in[3];
    const float* c2b  = (const float*)d_in[4];
    const float* er1w = (const float*)d_in[5];
    const float* er1b = (const float*)d_in[6];
    const float* er2w = (const float*)d_in[7];
    const float* er2b = (const float*)d_in[8];
    const float* cb   = (const float*)d_in[9];
    const float* dr1w = (const float*)d_in[10];
    const float* dr1b = (const float*)d_in[11];
    const float* dr2w = (const float*)d_in[12];
    const float* dr2b = (const float*)d_in[13];
    const float* t1w  = (const float*)d_in[14];
    const float* t1b  = (const float*)d_in[15];
    const float* t2w  = (const float*)d_in[16];
    const float* t2b  = (const float*)d_in[17];

    char* W = (char*)d_ws;                       // 256 MiB
    const size_t MB = 1024 * 1024;
    unsigned short* f1h   = (unsigned short*)(W + 0);
    unsigned short* f1l   = (unsigned short*)(W + 32 * MB);
    float*          f2c   = (float*)         (W + 64 * MB);
    float*          fer1  = (float*)         (W + 80 * MB);
    float*          fer2  = (float*)         (W + 96 * MB);
    unsigned short* qn    = (unsigned short*)(W + 112 * MB);
    unsigned short* qc    = (unsigned short*)(W + 128 * MB);
    unsigned short* d1o   = (unsigned short*)(W + 144 * MB);
    unsigned short* d2o   = (unsigned short*)(W + 160 * MB);
    unsigned short* t1o   = (unsigned short*)(W + 176 * MB);

    float* out     = (float*)d_out;
    float* idx_out = out + 4194304;

    conv1_k      <<<4096, 256, 0, stream>>>(x, c1w, c1b, f1h, f1l);
    conv2_mfma_k <<<2048, 256, 0, stream>>>(f1h, f1l, c2w, c2b, f2c);
    res_k        <<<2048, 256, 0, stream>>>(f2c, er1w, er1b, fer1);   // er1 (exact fp32)
    res_k        <<<2048, 256, 0, stream>>>(fer1, er2w, er2b, fer2);  // er2 (exact fp32)
    vq_k         <<<1024, 256, 0, stream>>>(fer2, cb, qn, idx_out);   // argmin exact
    trans_k      <<<4096, 256, 0, stream>>>(qn, qc);                  // -> ch-last bf16
    res_mfma_k   <<< 512, 256, 0, stream>>>(qc, dr1w, dr1b, d1o);     // dr1 (bf16 MFMA v2)
    res_mfma_k   <<< 512, 256, 0, stream>>>(d1o, dr2w, dr2b, d2o);    // dr2 (bf16 MFMA v2)
    tconv1_mfma_k<<<2048, 256, 0, stream>>>(d2o, t1w, t1b, t1o);
    tconv2_quad_k<<<4096, 256, 0, stream>>>(t1o, t2w, t2b, out);
}

// Round 24
// 214.056 us; speedup vs baseline: 1.5680x; 1.0435x over previous
//
#include <hip/hip_runtime.h>
#include <hip/hip_bf16.h>

// VQ-VAE forward, B=64, F=16.  d_out = float*: decoded 4194304 f32, indices 262144 f32.  ws = 256 MiB.
// R24: er1/er2 -> split-bf16 MFMA (3-chain Dekker, pattern validated on conv2 in R20 with exact
//      indices). conv2_mfma now emits hi/lo bf16 ch-last; er_mfma<0> emits hi/lo ch-last; er_mfma<1>
//      emits fp32 NCHW for exact vq argmin. Weights split into LDS (conv2 pattern, KP=176 pad).
// Pre-commit: Output1 fails -> revert er chain to R23 scalar, encoder numerics frozen thereafter.
// Lessons: uniform weights->SGPR (R10); matrix pipe beats scalar wall (R17/R20); hoist/stage frag
//      sources (R21->R22); merge parity classes to share reads (R23); small-state or bust.

#define R8X(M)  M(0) M(1) M(2) M(3) M(4) M(5) M(6) M(7)

typedef __attribute__((ext_vector_type(8))) short          bf16x8;
typedef __attribute__((ext_vector_type(8))) unsigned short u16x8;
typedef __attribute__((ext_vector_type(4))) float          f32x4;

__device__ __forceinline__ unsigned short f2bf(float f) {   // RNE fp32 -> bf16 bits
    unsigned u; __builtin_memcpy(&u, &f, 4);
    unsigned r = u + 0x7FFFu + ((u >> 16) & 1u);
    return (unsigned short)(r >> 16);
}
__device__ __forceinline__ float bf2f(unsigned short h) {
    unsigned u = ((unsigned)h) << 16;
    float f; __builtin_memcpy(&f, &u, 4);
    return f;
}

// ---------------- conv1: 1->16, 256->128 — hi/lo bf16 CHANNEL-LAST planes ----------------
__global__ __launch_bounds__(256) void conv1_k(const float* __restrict__ x, const float* __restrict__ w,
                                               const float* __restrict__ bias,
                                               unsigned short* __restrict__ oh, unsigned short* __restrict__ ol) {
    int idx = blockIdx.x * 256 + threadIdx.x;   // 64*128*128
    int ox = idx & 127;
    int oy = (idx >> 7) & 127;
    int b  = idx >> 14;
    const float* xin = x + (size_t)b * 65536;
    float pv[16];
#pragma unroll
    for (int ky = 0; ky < 4; ++ky) {
        int iy = 2 * oy - 1 + ky;
#pragma unroll
        for (int kx = 0; kx < 4; ++kx) {
            int ix = 2 * ox - 1 + kx;
            pv[ky * 4 + kx] = (iy >= 0 && iy < 256 && ix >= 0 && ix < 256)
                                  ? xin[iy * 256 + ix] : 0.f;
        }
    }
    u16x8 h0, h1, l0, l1;
#pragma unroll
    for (int oc = 0; oc < 16; ++oc) {
        float acc = bias[oc];
#pragma unroll
        for (int k = 0; k < 16; ++k) acc = fmaf(pv[k], w[oc * 16 + k], acc);
        float r = fmaxf(acc, 0.f);
        unsigned short hb = f2bf(r);
        unsigned short lb = f2bf(r - bf2f(hb));
        if (oc < 8) { h0[oc] = hb; l0[oc] = lb; }
        else        { h1[oc - 8] = hb; l1[oc - 8] = lb; }
    }
    u16x8* po = (u16x8*)(oh + (size_t)idx * 16);
    po[0] = h0; po[1] = h1;
    u16x8* pl = (u16x8*)(ol + (size_t)idx * 16);
    pl[0] = l0; pl[1] = l1;
}

// ---------------- conv2 via split-bf16 MFMA: K=256, 3 chains — hi/lo ch-last OUT ----------------
__global__ __launch_bounds__(256) void conv2_mfma_k(const unsigned short* __restrict__ fh,
                                                    const unsigned short* __restrict__ fl,
                                                    const float* __restrict__ w, const float* __restrict__ bias,
                                                    unsigned short* __restrict__ oh, unsigned short* __restrict__ ol) {
    __shared__ unsigned short wsh[16 * 264];
    __shared__ unsigned short wsl[16 * 264];
    for (int i = threadIdx.x; i < 4096; i += 256) {
        int oc = i >> 8, k = i & 255;
        int ic = k & 15, tap = k >> 4;
        float f = w[oc * 256 + ic * 16 + tap];
        unsigned short hb = f2bf(f);
        wsh[oc * 264 + k] = hb;
        wsl[oc * 264 + k] = f2bf(f - bf2f(hb));
    }
    __syncthreads();

    int wid  = threadIdx.x >> 6;
    int lane = threadIdx.x & 63;
    int col = lane & 15;
    int kg  = lane >> 4;
    int ic0 = (kg & 1) * 8;
    float accb = bias[col];
    int gw = blockIdx.x * 4 + wid;

    for (int t = 0; t < 2; ++t) {
        int tile = gw * 2 + t;
        int v0  = (tile & 3) * 16;
        int y   = (tile >> 2) & 63;
        int img = tile >> 8;
        const unsigned short* bh = fh + (size_t)img * 262144;
        const unsigned short* bl = fl + (size_t)img * 262144;
        f32x4 acc = { accb, accb, accb, accb };
#pragma unroll
        for (int m = 0; m < 8; ++m) {
            int tap = 2 * m + (kg >> 1);
            int ty = tap >> 2, tx = tap & 3;
            int jy = 2 * y - 1 + ty;
            int jx = 2 * (v0 + col) - 1 + tx;
            bf16x8 ah = { 0, 0, 0, 0, 0, 0, 0, 0 };
            bf16x8 al = { 0, 0, 0, 0, 0, 0, 0, 0 };
            if (jy >= 0 && jy < 128 && jx >= 0 && jx < 128) {
                size_t off = ((size_t)(jy * 128 + jx)) * 16 + ic0;
                ah = *(const bf16x8*)(bh + off);
                al = *(const bf16x8*)(bl + off);
            }
            bf16x8 wh = *(const bf16x8*)&wsh[col * 264 + m * 32 + kg * 8];
            bf16x8 wl = *(const bf16x8*)&wsl[col * 264 + m * 32 + kg * 8];
            acc = __builtin_amdgcn_mfma_f32_16x16x32_bf16(ah, wh, acc, 0, 0, 0);
            acc = __builtin_amdgcn_mfma_f32_16x16x32_bf16(al, wh, acc, 0, 0, 0);
            acc = __builtin_amdgcn_mfma_f32_16x16x32_bf16(ah, wl, acc, 0, 0, 0);
        }
#pragma unroll
        for (int r = 0; r < 4; ++r) {
            int xx = v0 + kg * 4 + r;
            size_t ad = (size_t)img * 65536 + ((size_t)(y * 64 + xx)) * 16 + col;   // ch-last
            float rv = fmaxf(acc[r], 0.f);
            unsigned short hb = f2bf(rv);
            oh[ad] = hb;
            ol[ad] = f2bf(rv - bf2f(hb));
        }
    }
}

// ---------------- er res via split-bf16 MFMA: K=144 pad 176, 3 chains, LDS weights ----------------
// in: hi/lo ch-last (64,64,64,16). OUTMODE 0: hi/lo ch-last out. OUTMODE 1: fp32 NCHW out (for VQ).
template <int OUTMODE>
__global__ __launch_bounds__(256) void er_mfma_k(const unsigned short* __restrict__ inh,
                                                 const unsigned short* __restrict__ inl,
                                                 const float* __restrict__ w, const float* __restrict__ bias,
                                                 unsigned short* __restrict__ oh, unsigned short* __restrict__ ol,
                                                 float* __restrict__ ofp) {
    __shared__ unsigned short wsh[16 * 176];
    __shared__ unsigned short wsl[16 * 176];
    for (int i = threadIdx.x; i < 2816; i += 256) {
        int oc = i / 176, k = i % 176;
        float f = (k < 144) ? w[(oc * 16 + (k & 15)) * 9 + (k >> 4)] : 0.f;
        unsigned short hb = f2bf(f);
        wsh[i] = hb;
        wsl[i] = f2bf(f - bf2f(hb));
    }
    __syncthreads();

    int wid  = threadIdx.x >> 6;
    int lane = threadIdx.x & 63;
    int col = lane & 15;                 // A px-row / C oc-col
    int kg  = lane >> 4;
    int ic0 = (kg & 1) * 8;
    float accb = bias[col];
    int gw = blockIdx.x * 4 + wid;       // 2048 waves x 8 tiles = 16384 tiles

    for (int t = 0; t < 8; ++t) {
        int tile = gw * 8 + t;
        int v0  = (tile & 3) * 16;
        int y   = (tile >> 2) & 63;
        int img = tile >> 8;
        const unsigned short* xh = inh + (size_t)img * 65536;
        const unsigned short* xl = inl + (size_t)img * 65536;
        f32x4 acc = { accb, accb, accb, accb };
#pragma unroll
        for (int m = 0; m < 5; ++m) {
            int tap = 2 * m + (kg >> 1);     // 0..9, tap 9 = zero pad
            bf16x8 ah = { 0, 0, 0, 0, 0, 0, 0, 0 };
            bf16x8 al = { 0, 0, 0, 0, 0, 0, 0, 0 };
            if (tap < 9) {
                int ty = tap / 3, tx = tap - ty * 3;
                int jy = y + ty - 1;
                int jx = v0 + col + tx - 1;
                if (jy >= 0 && jy < 64 && jx >= 0 && jx < 64) {
                    size_t off = ((size_t)(jy * 64 + jx)) * 16 + ic0;
                    ah = *(const bf16x8*)(xh + off);
                    al = *(const bf16x8*)(xl + off);
                }
            }
            bf16x8 wh = *(const bf16x8*)&wsh[col * 176 + m * 32 + kg * 8];
            bf16x8 wl = *(const bf16x8*)&wsl[col * 176 + m * 32 + kg * 8];
            acc = __builtin_amdgcn_mfma_f32_16x16x32_bf16(ah, wh, acc, 0, 0, 0);
            acc = __builtin_amdgcn_mfma_f32_16x16x32_bf16(al, wh, acc, 0, 0, 0);
            acc = __builtin_amdgcn_mfma_f32_16x16x32_bf16(ah, wl, acc, 0, 0, 0);
        }
#pragma unroll
        for (int r = 0; r < 4; ++r) {
            int px = v0 + kg * 4 + r;
            size_t ad = ((size_t)(y * 64 + px)) * 16 + col;
            float vin = bf2f(xh[ad]) + bf2f(xl[ad]);
            float res = vin + fmaxf(acc[r], 0.f);
            if (OUTMODE == 0) {
                unsigned short hb = f2bf(res);
                oh[(size_t)img * 65536 + ad] = hb;
                ol[(size_t)img * 65536 + ad] = f2bf(res - bf2f(hb));
            } else {
                ofp[(size_t)img * 65536 + (size_t)col * 4096 + y * 64 + px] = res;   // NCHW
            }
        }
    }
}

// ---------------- VQ: rows of 16 contiguous floats (raw NCHW flatten), K=64 — bf16 NCHW q out ----------------
__global__ __launch_bounds__(256) void vq_k(const float* __restrict__ h, const float* __restrict__ cb,
                                            unsigned short* __restrict__ q, float* __restrict__ idx_out) {
    __shared__ float cbs[1024];  // 64 x 16
    __shared__ float cn[64];
    for (int i = threadIdx.x; i < 1024; i += 256) cbs[i] = cb[i];
    __syncthreads();
    if (threadIdx.x < 64) {
        float s = 0.f;
#pragma unroll
        for (int d = 0; d < 16; ++d) { float v = cbs[threadIdx.x * 16 + d]; s = fmaf(v, v, s); }
        cn[threadIdx.x] = s;
    }
    __syncthreads();
    int r = blockIdx.x * 256 + threadIdx.x;   // 262144 rows
    float f[16];
    const float4* hp = (const float4*)(h + (size_t)r * 16);
#pragma unroll
    for (int j = 0; j < 4; ++j) {
        float4 v = hp[j];
        f[j * 4 + 0] = v.x; f[j * 4 + 1] = v.y; f[j * 4 + 2] = v.z; f[j * 4 + 3] = v.w;
    }
    float best = 3.4e38f;
    int bi = 0;
    for (int k = 0; k < 64; ++k) {
        float dot = 0.f;
#pragma unroll
        for (int d = 0; d < 16; ++d) dot = fmaf(f[d], cbs[k * 16 + d], dot);
        float dist = cn[k] - 2.f * dot;   // +||f||^2 per-row constant, argmin-invariant
        if (dist < best) { best = dist; bi = k; }
    }
    u16x8 q0, q1;
#pragma unroll
    for (int d = 0; d < 8; ++d) {
        q0[d] = f2bf(cbs[bi * 16 + d]);
        q1[d] = f2bf(cbs[bi * 16 + 8 + d]);
    }
    u16x8* qp = (u16x8*)(q + (size_t)r * 16);
    qp[0] = q0; qp[1] = q1;
    idx_out[r] = (float)bi;
}

// ---------------- transpose: (64,16,64,64) bf16 NCHW -> (64,64,64,16) bf16 ch-last ----------------
__global__ __launch_bounds__(256) void trans_k(const unsigned short* __restrict__ in,
                                               unsigned short* __restrict__ out) {
    __shared__ unsigned short lds[16 * 64];
    int b = blockIdx.x >> 6;
    int y = blockIdx.x & 63;
    int t = threadIdx.x;
    {
        int c = t >> 4, x0 = (t & 15) * 4;
        const unsigned short* p = in + (((size_t)(b * 16 + c) * 64 + y) << 6) + x0;
#pragma unroll
        for (int j = 0; j < 4; ++j) lds[c * 64 + x0 + j] = p[j];
    }
    __syncthreads();
    {
        int xx = t >> 2, c0 = (t & 3) * 4;
        unsigned short* p = out + (((size_t)(b * 64 + y) * 64 + xx) << 4) + c0;
#pragma unroll
        for (int j = 0; j < 4; ++j) p[j] = lds[(c0 + j) * 64 + xx];
    }
}

// ---------------- res via plain bf16 MFMA (decoder): B-frags hoisted, 8 tiles/wave ----------------
__global__ __launch_bounds__(256) void res_mfma_k(const unsigned short* __restrict__ in,
                                                  const float* __restrict__ w, const float* __restrict__ bias,
                                                  unsigned short* __restrict__ outb) {
    int wid  = threadIdx.x >> 6;
    int lane = threadIdx.x & 63;
    int col = lane & 15;
    int kg  = lane >> 4;
    int ic0 = (kg & 1) * 8;

    bf16x8 bw[5];
#pragma unroll
    for (int m = 0; m < 5; ++m) {
        int tap = 2 * m + (kg >> 1);
        bf16x8 t = { 0, 0, 0, 0, 0, 0, 0, 0 };
        if (tap < 9) {
#pragma unroll
            for (int j = 0; j < 8; ++j)
                t[j] = (short)f2bf(w[(col * 16 + ic0 + j) * 9 + tap]);
        }
        bw[m] = t;
    }
    float accb = bias[col];

    int gw = blockIdx.x * 4 + wid;       // 2048 waves x 8 tiles
    for (int t = 0; t < 8; ++t) {
        int tile = gw * 8 + t;
        int v0  = (tile & 3) * 16;
        int y   = (tile >> 2) & 63;
        int img = tile >> 8;
        const unsigned short* xi = in + (size_t)img * 65536;
        f32x4 acc = { accb, accb, accb, accb };
#pragma unroll
        for (int m = 0; m < 5; ++m) {
            int tap = 2 * m + (kg >> 1);
            bf16x8 a = { 0, 0, 0, 0, 0, 0, 0, 0 };
            if (tap < 9) {
                int ty = tap / 3, tx = tap - ty * 3;
                int jy = y + ty - 1;
                int jx = v0 + col + tx - 1;
                if (jy >= 0 && jy < 64 && jx >= 0 && jx < 64)
                    a = *(const bf16x8*)(xi + ((jy * 64 + jx) * 16 + ic0));
            }
            acc = __builtin_amdgcn_mfma_f32_16x16x32_bf16(a, bw[m], acc, 0, 0, 0);
        }
#pragma unroll
        for (int r = 0; r < 4; ++r) {
            int px = v0 + kg * 4 + r;
            size_t ad = (size_t)(y * 64 + px) * 16 + col;
            float vin = bf2f(xi[ad]);
            outb[(size_t)img * 65536 + ad] = f2bf(vin + fmaxf(acc[r], 0.f));
        }
    }
}

// ---------------- tconv1 via MFMA: per parity class GEMM — bf16 out ----------------
__global__ __launch_bounds__(256) void tconv1_mfma_k(const unsigned short* __restrict__ xb,
                                                     const float* __restrict__ w1, const float* __restrict__ bia,
                                                     unsigned short* __restrict__ outb) {
    int cls = blockIdx.x >> 9;           // 4 classes x 512 blocks
    int bb  = blockIdx.x & 511;
    int DY = cls >> 1, DX = cls & 1;
    int wid  = threadIdx.x >> 6;
    int lane = threadIdx.x & 63;
    int oc = lane & 15;
    int kg = lane >> 4;

    bf16x8 bfr0, bfr1;
    float accb = bia[oc];
#pragma unroll
    for (int m = 0; m < 2; ++m) {
        int tap = 2 * m + (kg >> 1);
        int ty = tap >> 1, tx = tap & 1;
        int koff = (3 - DY - 2 * ty) * 4 + (3 - DX - 2 * tx);
        int ic0 = (kg & 1) * 8;
        bf16x8 t;
#pragma unroll
        for (int j = 0; j < 8; ++j)
            t[j] = (short)f2bf(w1[(ic0 + j) * 256 + oc * 16 + koff]);
        if (m == 0) bfr0 = t; else bfr1 = t;
    }

    int Wc = bb * 4 + wid;
    for (int t = 0; t < 8; ++t) {
        int tile = Wc * 8 + t;
        int v0  = (tile & 3) * 16;
        int u   = (tile >> 2) & 63;
        int img = tile >> 8;
        const unsigned short* xi = xb + (size_t)img * 65536;
        f32x4 acc = { accb, accb, accb, accb };
#pragma unroll
        for (int m = 0; m < 2; ++m) {
            int tap = 2 * m + (kg >> 1);
            int ty = tap >> 1, tx = tap & 1;
            int jy = u + DY - 1 + ty;
            int jx = v0 + oc + DX - 1 + tx;
            bf16x8 a = { 0, 0, 0, 0, 0, 0, 0, 0 };
            if (jy >= 0 && jy < 64 && jx >= 0 && jx < 64) {
                int ic0 = (kg & 1) * 8;
                a = *(const bf16x8*)(xi + ((jy * 64 + jx) * 16 + ic0));
            }
            acc = __builtin_amdgcn_mfma_f32_16x16x32_bf16(a, (m == 0 ? bfr0 : bfr1), acc, 0, 0, 0);
        }
        int my = 2 * u + DY;
#pragma unroll
        for (int r = 0; r < 4; ++r) {
            int pxr = kg * 4 + r;
            int mx  = 2 * (v0 + pxr) + DX;
            outb[(((size_t)img * 16384) + my * 128 + mx) * 16 + oc] = f2bf(fmaxf(acc[r], 0.f));
        }
    }
}

// ---------------- tconv2: 2x2-quad kernel — 3x3 shared neighborhood, contiguous stores ----------------
template <int RY, int RX>
__device__ __forceinline__ void quad_contrib(const unsigned short* __restrict__ px,
                                             const float* __restrict__ w2,
                                             float& a00, float& a01, float& a10, float& a11) {
    constexpr int nY = (RY == 0) ? 2 : 1;
    constexpr int nX = (RX == 0) ? 2 : 1;
    constexpr int dyA[2] = { (RY == 1) ? 1 : 0, 1 };
    constexpr int kyA[2] = { (RY == -1) ? 3 : ((RY == 0) ? 1 : 0), 2 };
    constexpr int dxA[2] = { (RX == 1) ? 1 : 0, 1 };
    constexpr int kxA[2] = { (RX == -1) ? 3 : ((RX == 0) ? 1 : 0), 2 };
    u16x8 h0 = *(const u16x8*)px;
    u16x8 h1 = *(const u16x8*)(px + 8);
#pragma unroll
    for (int iy = 0; iy < nY; ++iy) {
#pragma unroll
        for (int ix = 0; ix < nX; ++ix) {
            const int ky = kyA[iy], kx = kxA[ix];
            float& a = (dyA[iy] == 0) ? ((dxA[ix] == 0) ? a00 : a01)
                                      : ((dxA[ix] == 0) ? a10 : a11);
#pragma unroll
            for (int ic = 0; ic < 8; ++ic)
                a = fmaf(bf2f(h0[ic]), w2[ic * 16 + ky * 4 + kx], a);
#pragma unroll
            for (int ic = 0; ic < 8; ++ic)
                a = fmaf(bf2f(h1[ic]), w2[(ic + 8) * 16 + ky * 4 + kx], a);
        }
    }
}

__global__ __launch_bounds__(256) void tconv2_quad_k(const unsigned short* __restrict__ f1b,
                                                     const float* __restrict__ w2, const float* __restrict__ b2,
                                                     float* __restrict__ out) {
    int idx = blockIdx.x * 256 + threadIdx.x;   // 64 img * 128*128 quads
    int v = idx & 127;
    int u = (idx >> 7) & 127;
    int b = idx >> 14;
    const unsigned short* fb = f1b + (size_t)b * 262144;
    float b2s = b2[0];
    float a00 = b2s, a01 = b2s, a10 = b2s, a11 = b2s;

#define QC(RY, RX) { int jy = u + (RY), jx = v + (RX); \
    if (jy >= 0 && jy < 128 && jx >= 0 && jx < 128) \
        quad_contrib<RY, RX>(fb + ((size_t)(jy * 128 + jx) << 4), w2, a00, a01, a10, a11); }
    QC(-1, -1) QC(-1, 0) QC(-1, 1)
    QC( 0, -1) QC( 0, 0) QC( 0, 1)
    QC( 1, -1) QC( 1, 0) QC( 1, 1)
#undef QC

    float* o = out + (size_t)b * 65536 + (2 * u) * 256 + 2 * v;
    float2 r0; r0.x = a00; r0.y = a01;
    float2 r1; r1.x = a10; r1.y = a11;
    *(float2*)o         = r0;
    *(float2*)(o + 256) = r1;
}

extern "C" void kernel_launch(void* const* d_in, const int* in_sizes, int n_in,
                              void* d_out, int out_size, void* d_ws, size_t ws_size,
                              hipStream_t stream) {
    const float* x    = (const float*)d_in[0];
    const float* c1w  = (const float*)d_in[1];
    const float* c1b  = (const float*)d_in[2];
    const float* c2w  = (const float*)d_in[3];
    const float* c2b  = (const float*)d_in[4];
    const float* er1w = (const float*)d_in[5];
    const float* er1b = (const float*)d_in[6];
    const float* er2w = (const float*)d_in[7];
    const float* er2b = (const float*)d_in[8];
    const float* cb   = (const float*)d_in[9];
    const float* dr1w = (const float*)d_in[10];
    const float* dr1b = (const float*)d_in[11];
    const float* dr2w = (const float*)d_in[12];
    const float* dr2b = (const float*)d_in[13];
    const float* t1w  = (const float*)d_in[14];
    const float* t1b  = (const float*)d_in[15];
    const float* t2w  = (const float*)d_in[16];
    const float* t2b  = (const float*)d_in[17];

    char* W = (char*)d_ws;                       // 256 MiB (R20 fill evidence)
    const size_t MB = 1024 * 1024;
    unsigned short* f1h = (unsigned short*)(W + 0);          // conv1 hi (64,128,128,16) bf16, 32 MiB
    unsigned short* f1l = (unsigned short*)(W + 32 * MB);    // conv1 lo
    unsigned short* c2h = (unsigned short*)(W + 64 * MB);    // conv2 hi (64,64,64,16) ch-last, 8.4 MB
    unsigned short* c2l = (unsigned short*)(W + 80 * MB);    // conv2 lo
    unsigned short* e1h = (unsigned short*)(W + 96 * MB);    // er1 hi ch-last
    unsigned short* e1l = (unsigned short*)(W + 112 * MB);   // er1 lo
    float*          e2f = (float*)         (W + 128 * MB);   // er2 fp32 NCHW (VQ input), 16.8 MB
    unsigned short* qn  = (unsigned short*)(W + 152 * MB);   // quantized bf16 NCHW
    unsigned short* qc  = (unsigned short*)(W + 168 * MB);   // quantized bf16 ch-last
    unsigned short* d1o = (unsigned short*)(W + 184 * MB);   // dr1 out ch-last bf16
    unsigned short* d2o = (unsigned short*)(W + 200 * MB);   // dr2 out ch-last bf16
    unsigned short* t1o = (unsigned short*)(W + 216 * MB);   // tconv1 out (64,128,128,16) bf16, 33.5 MB

    float* out     = (float*)d_out;
    float* idx_out = out + 4194304;

    conv1_k      <<<4096, 256, 0, stream>>>(x, c1w, c1b, f1h, f1l);
    conv2_mfma_k <<<2048, 256, 0, stream>>>(f1h, f1l, c2w, c2b, c2h, c2l);
    er_mfma_k<0> <<< 512, 256, 0, stream>>>(c2h, c2l, er1w, er1b, e1h, e1l, nullptr);  // er1
    er_mfma_k<1> <<< 512, 256, 0, stream>>>(e1h, e1l, er2w, er2b, nullptr, nullptr, e2f); // er2 -> fp32 NCHW
    vq_k         <<<1024, 256, 0, stream>>>(e2f, cb, qn, idx_out);    // argmin (exact given e2f)
    trans_k      <<<4096, 256, 0, stream>>>(qn, qc);                  // -> ch-last bf16
    res_mfma_k   <<< 512, 256, 0, stream>>>(qc, dr1w, dr1b, d1o);     // dr1 (bf16 MFMA)
    res_mfma_k   <<< 512, 256, 0, stream>>>(d1o, dr2w, dr2b, d2o);    // dr2 (bf16 MFMA)
    tconv1_mfma_k<<<2048, 256, 0, stream>>>(d2o, t1w, t1b, t1o);
    tconv2_quad_k<<<4096, 256, 0, stream>>>(t1o, t2w, t2b, out);
}

// Round 25
// 202.718 us; speedup vs baseline: 1.6557x; 1.0559x over previous
//
#include <hip/hip_runtime.h>
#include <hip/hip_bf16.h>

// VQ-VAE forward, B=64, F=16.  d_out = float*: decoded 4194304 f32, indices 262144 f32.  ws = 256 MiB.
// R25: (1) vq_k fused with transpose — block = (img, 4-row band); exact sequential argmin math
//      unchanged (bit-identical indices); codes staged via LDS and written ch-last bf16 coalesced.
//      trans_k + qn eliminated (-17MB, -1 launch). (2) er_mfma/res_mfma: 1024 blocks x 4 tiles/wave
//      (was 512x8 = 2 waves/SIMD, latency-exposed).
// Lessons: uniform weights->SGPR (R10); matrix pipe beats scalar wall (R17/R20); hoist frag builds
//      (R22); merge parity classes to share reads (R23); split-bf16 Dekker = index-exact (R20/R24).

#define R8X(M)  M(0) M(1) M(2) M(3) M(4) M(5) M(6) M(7)

typedef __attribute__((ext_vector_type(8))) short          bf16x8;
typedef __attribute__((ext_vector_type(8))) unsigned short u16x8;
typedef __attribute__((ext_vector_type(4))) float          f32x4;

__device__ __forceinline__ unsigned short f2bf(float f) {   // RNE fp32 -> bf16 bits
    unsigned u; __builtin_memcpy(&u, &f, 4);
    unsigned r = u + 0x7FFFu + ((u >> 16) & 1u);
    return (unsigned short)(r >> 16);
}
__device__ __forceinline__ float bf2f(unsigned short h) {
    unsigned u = ((unsigned)h) << 16;
    float f; __builtin_memcpy(&f, &u, 4);
    return f;
}

// ---------------- conv1: 1->16, 256->128 — hi/lo bf16 CHANNEL-LAST planes ----------------
__global__ __launch_bounds__(256) void conv1_k(const float* __restrict__ x, const float* __restrict__ w,
                                               const float* __restrict__ bias,
                                               unsigned short* __restrict__ oh, unsigned short* __restrict__ ol) {
    int idx = blockIdx.x * 256 + threadIdx.x;   // 64*128*128
    int ox = idx & 127;
    int oy = (idx >> 7) & 127;
    int b  = idx >> 14;
    const float* xin = x + (size_t)b * 65536;
    float pv[16];
#pragma unroll
    for (int ky = 0; ky < 4; ++ky) {
        int iy = 2 * oy - 1 + ky;
#pragma unroll
        for (int kx = 0; kx < 4; ++kx) {
            int ix = 2 * ox - 1 + kx;
            pv[ky * 4 + kx] = (iy >= 0 && iy < 256 && ix >= 0 && ix < 256)
                                  ? xin[iy * 256 + ix] : 0.f;
        }
    }
    u16x8 h0, h1, l0, l1;
#pragma unroll
    for (int oc = 0; oc < 16; ++oc) {
        float acc = bias[oc];
#pragma unroll
        for (int k = 0; k < 16; ++k) acc = fmaf(pv[k], w[oc * 16 + k], acc);
        float r = fmaxf(acc, 0.f);
        unsigned short hb = f2bf(r);
        unsigned short lb = f2bf(r - bf2f(hb));
        if (oc < 8) { h0[oc] = hb; l0[oc] = lb; }
        else        { h1[oc - 8] = hb; l1[oc - 8] = lb; }
    }
    u16x8* po = (u16x8*)(oh + (size_t)idx * 16);
    po[0] = h0; po[1] = h1;
    u16x8* pl = (u16x8*)(ol + (size_t)idx * 16);
    pl[0] = l0; pl[1] = l1;
}

// ---------------- conv2 via split-bf16 MFMA: K=256, 3 chains — hi/lo ch-last OUT ----------------
__global__ __launch_bounds__(256) void conv2_mfma_k(const unsigned short* __restrict__ fh,
                                                    const unsigned short* __restrict__ fl,
                                                    const float* __restrict__ w, const float* __restrict__ bias,
                                                    unsigned short* __restrict__ oh, unsigned short* __restrict__ ol) {
    __shared__ unsigned short wsh[16 * 264];
    __shared__ unsigned short wsl[16 * 264];
    for (int i = threadIdx.x; i < 4096; i += 256) {
        int oc = i >> 8, k = i & 255;
        int ic = k & 15, tap = k >> 4;
        float f = w[oc * 256 + ic * 16 + tap];
        unsigned short hb = f2bf(f);
        wsh[oc * 264 + k] = hb;
        wsl[oc * 264 + k] = f2bf(f - bf2f(hb));
    }
    __syncthreads();

    int wid  = threadIdx.x >> 6;
    int lane = threadIdx.x & 63;
    int col = lane & 15;
    int kg  = lane >> 4;
    int ic0 = (kg & 1) * 8;
    float accb = bias[col];
    int gw = blockIdx.x * 4 + wid;

    for (int t = 0; t < 2; ++t) {
        int tile = gw * 2 + t;
        int v0  = (tile & 3) * 16;
        int y   = (tile >> 2) & 63;
        int img = tile >> 8;
        const unsigned short* bh = fh + (size_t)img * 262144;
        const unsigned short* bl = fl + (size_t)img * 262144;
        f32x4 acc = { accb, accb, accb, accb };
#pragma unroll
        for (int m = 0; m < 8; ++m) {
            int tap = 2 * m + (kg >> 1);
            int ty = tap >> 2, tx = tap & 3;
            int jy = 2 * y - 1 + ty;
            int jx = 2 * (v0 + col) - 1 + tx;
            bf16x8 ah = { 0, 0, 0, 0, 0, 0, 0, 0 };
            bf16x8 al = { 0, 0, 0, 0, 0, 0, 0, 0 };
            if (jy >= 0 && jy < 128 && jx >= 0 && jx < 128) {
                size_t off = ((size_t)(jy * 128 + jx)) * 16 + ic0;
                ah = *(const bf16x8*)(bh + off);
                al = *(const bf16x8*)(bl + off);
            }
            bf16x8 wh = *(const bf16x8*)&wsh[col * 264 + m * 32 + kg * 8];
            bf16x8 wl = *(const bf16x8*)&wsl[col * 264 + m * 32 + kg * 8];
            acc = __builtin_amdgcn_mfma_f32_16x16x32_bf16(ah, wh, acc, 0, 0, 0);
            acc = __builtin_amdgcn_mfma_f32_16x16x32_bf16(al, wh, acc, 0, 0, 0);
            acc = __builtin_amdgcn_mfma_f32_16x16x32_bf16(ah, wl, acc, 0, 0, 0);
        }
#pragma unroll
        for (int r = 0; r < 4; ++r) {
            int xx = v0 + kg * 4 + r;
            size_t ad = (size_t)img * 65536 + ((size_t)(y * 64 + xx)) * 16 + col;   // ch-last
            float rv = fmaxf(acc[r], 0.f);
            unsigned short hb = f2bf(rv);
            oh[ad] = hb;
            ol[ad] = f2bf(rv - bf2f(hb));
        }
    }
}

// ---------------- er res via split-bf16 MFMA: K=144 pad 176, 1024 blocks x 4 tiles ----------------
template <int OUTMODE>
__global__ __launch_bounds__(256) void er_mfma_k(const unsigned short* __restrict__ inh,
                                                 const unsigned short* __restrict__ inl,
                                                 const float* __restrict__ w, const float* __restrict__ bias,
                                                 unsigned short* __restrict__ oh, unsigned short* __restrict__ ol,
                                                 float* __restrict__ ofp) {
    __shared__ unsigned short wsh[16 * 176];
    __shared__ unsigned short wsl[16 * 176];
    for (int i = threadIdx.x; i < 2816; i += 256) {
        int oc = i / 176, k = i % 176;
        float f = (k < 144) ? w[(oc * 16 + (k & 15)) * 9 + (k >> 4)] : 0.f;
        unsigned short hb = f2bf(f);
        wsh[i] = hb;
        wsl[i] = f2bf(f - bf2f(hb));
    }
    __syncthreads();

    int wid  = threadIdx.x >> 6;
    int lane = threadIdx.x & 63;
    int col = lane & 15;
    int kg  = lane >> 4;
    int ic0 = (kg & 1) * 8;
    float accb = bias[col];
    int gw = blockIdx.x * 4 + wid;       // 4096 waves x 4 tiles = 16384 tiles

    for (int t = 0; t < 4; ++t) {
        int tile = gw * 4 + t;
        int v0  = (tile & 3) * 16;
        int y   = (tile >> 2) & 63;
        int img = tile >> 8;
        const unsigned short* xh = inh + (size_t)img * 65536;
        const unsigned short* xl = inl + (size_t)img * 65536;
        f32x4 acc = { accb, accb, accb, accb };
#pragma unroll
        for (int m = 0; m < 5; ++m) {
            int tap = 2 * m + (kg >> 1);     // 0..9, tap 9 = zero pad
            bf16x8 ah = { 0, 0, 0, 0, 0, 0, 0, 0 };
            bf16x8 al = { 0, 0, 0, 0, 0, 0, 0, 0 };
            if (tap < 9) {
                int ty = tap / 3, tx = tap - ty * 3;
                int jy = y + ty - 1;
                int jx = v0 + col + tx - 1;
                if (jy >= 0 && jy < 64 && jx >= 0 && jx < 64) {
                    size_t off = ((size_t)(jy * 64 + jx)) * 16 + ic0;
                    ah = *(const bf16x8*)(xh + off);
                    al = *(const bf16x8*)(xl + off);
                }
            }
            bf16x8 wh = *(const bf16x8*)&wsh[col * 176 + m * 32 + kg * 8];
            bf16x8 wl = *(const bf16x8*)&wsl[col * 176 + m * 32 + kg * 8];
            acc = __builtin_amdgcn_mfma_f32_16x16x32_bf16(ah, wh, acc, 0, 0, 0);
            acc = __builtin_amdgcn_mfma_f32_16x16x32_bf16(al, wh, acc, 0, 0, 0);
            acc = __builtin_amdgcn_mfma_f32_16x16x32_bf16(ah, wl, acc, 0, 0, 0);
        }
#pragma unroll
        for (int r = 0; r < 4; ++r) {
            int px = v0 + kg * 4 + r;
            size_t ad = ((size_t)(y * 64 + px)) * 16 + col;
            float vin = bf2f(xh[ad]) + bf2f(xl[ad]);
            float res = vin + fmaxf(acc[r], 0.f);
            if (OUTMODE == 0) {
                unsigned short hb = f2bf(res);
                oh[(size_t)img * 65536 + ad] = hb;
                ol[(size_t)img * 65536 + ad] = f2bf(res - bf2f(hb));
            } else {
                ofp[(size_t)img * 65536 + (size_t)col * 4096 + y * 64 + px] = res;   // NCHW
            }
        }
    }
}

// ---------------- VQ fused with transpose: block = (img, 4-row band); ch-last bf16 q out ----------------
// Exact sequential argmin math (bit-identical to prior rounds). Rows: r = b*4096 + c*256 + y*4 + xc.
__global__ __launch_bounds__(256) void vq_k(const float* __restrict__ h, const float* __restrict__ cb,
                                            unsigned short* __restrict__ qc, float* __restrict__ idx_out) {
    __shared__ float cbs[1024];  // 64 x 16
    __shared__ float cn[64];
    __shared__ unsigned short st[4096];  // [yl][x][c] — matches ch-last chunk layout
    for (int i = threadIdx.x; i < 1024; i += 256) cbs[i] = cb[i];
    __syncthreads();
    if (threadIdx.x < 64) {
        float s = 0.f;
#pragma unroll
        for (int d = 0; d < 16; ++d) { float v = cbs[threadIdx.x * 16 + d]; s = fmaf(v, v, s); }
        cn[threadIdx.x] = s;
    }
    __syncthreads();

    int blk = blockIdx.x;                // 1024 = 64 img x 16 bands
    int b  = blk >> 4;
    int y0 = (blk & 15) * 4;             // 4 rows per band
    int t  = threadIdx.x;
    int c  = t >> 4;                     // channel 0..15
    int yl = (t >> 2) & 3;               // row-in-band
    int xc = t & 3;                      // x-chunk (16 px)
    int r  = b * 4096 + c * 256 + (y0 + yl) * 4 + xc;   // raw-flatten row id

    float f[16];
    const float4* hp = (const float4*)(h + (size_t)r * 16);
#pragma unroll
    for (int j = 0; j < 4; ++j) {
        float4 v = hp[j];
        f[j * 4 + 0] = v.x; f[j * 4 + 1] = v.y; f[j * 4 + 2] = v.z; f[j * 4 + 3] = v.w;
    }
    float best = 3.4e38f;
    int bi = 0;
    for (int k = 0; k < 64; ++k) {
        float dot = 0.f;
#pragma unroll
        for (int d = 0; d < 16; ++d) dot = fmaf(f[d], cbs[k * 16 + d], dot);
        float dist = cn[k] - 2.f * dot;   // +||f||^2 per-row constant, argmin-invariant
        if (dist < best) { best = dist; bi = k; }
    }
    idx_out[r] = (float)bi;

    // stage codes: quantized[b][c][y0+yl][xc*16+j] = cb[bi][j]  ->  st[((yl*64)+(xc*16+j))*16 + c]
#pragma unroll
    for (int j = 0; j < 16; ++j)
        st[((yl * 64) + (xc * 16 + j)) * 16 + c] = f2bf(cbs[bi * 16 + j]);
    __syncthreads();

    // coalesced ch-last write: contiguous 4096 u16 at ((b*64+y0)*64)*16
    u16x8* dst = (u16x8*)(qc + (((size_t)(b * 64 + y0)) * 64) * 16);
    const u16x8* src = (const u16x8*)st;
#pragma unroll
    for (int i = 0; i < 2; ++i)
        dst[t + 256 * i] = src[t + 256 * i];
}

// ---------------- res via plain bf16 MFMA (decoder): 1024 blocks x 4 tiles ----------------
__global__ __launch_bounds__(256) void res_mfma_k(const unsigned short* __restrict__ in,
                                                  const float* __restrict__ w, const float* __restrict__ bias,
                                                  unsigned short* __restrict__ outb) {
    int wid  = threadIdx.x >> 6;
    int lane = threadIdx.x & 63;
    int col = lane & 15;
    int kg  = lane >> 4;
    int ic0 = (kg & 1) * 8;

    bf16x8 bw[5];
#pragma unroll
    for (int m = 0; m < 5; ++m) {
        int tap = 2 * m + (kg >> 1);
        bf16x8 t = { 0, 0, 0, 0, 0, 0, 0, 0 };
        if (tap < 9) {
#pragma unroll
            for (int j = 0; j < 8; ++j)
                t[j] = (short)f2bf(w[(col * 16 + ic0 + j) * 9 + tap]);
        }
        bw[m] = t;
    }
    float accb = bias[col];

    int gw = blockIdx.x * 4 + wid;       // 4096 waves x 4 tiles
    for (int t = 0; t < 4; ++t) {
        int tile = gw * 4 + t;
        int v0  = (tile & 3) * 16;
        int y   = (tile >> 2) & 63;
        int img = tile >> 8;
        const unsigned short* xi = in + (size_t)img * 65536;
        f32x4 acc = { accb, accb, accb, accb };
#pragma unroll
        for (int m = 0; m < 5; ++m) {
            int tap = 2 * m + (kg >> 1);
            bf16x8 a = { 0, 0, 0, 0, 0, 0, 0, 0 };
            if (tap < 9) {
                int ty = tap / 3, tx = tap - ty * 3;
                int jy = y + ty - 1;
                int jx = v0 + col + tx - 1;
                if (jy >= 0 && jy < 64 && jx >= 0 && jx < 64)
                    a = *(const bf16x8*)(xi + ((jy * 64 + jx) * 16 + ic0));
            }
            acc = __builtin_amdgcn_mfma_f32_16x16x32_bf16(a, bw[m], acc, 0, 0, 0);
        }
#pragma unroll
        for (int r = 0; r < 4; ++r) {
            int px = v0 + kg * 4 + r;
            size_t ad = (size_t)(y * 64 + px) * 16 + col;
            float vin = bf2f(xi[ad]);
            outb[(size_t)img * 65536 + ad] = f2bf(vin + fmaxf(acc[r], 0.f));
        }
    }
}

// ---------------- tconv1 via MFMA: per parity class GEMM — bf16 out ----------------
__global__ __launch_bounds__(256) void tconv1_mfma_k(const unsigned short* __restrict__ xb,
                                                     const float* __restrict__ w1, const float* __restrict__ bia,
                                                     unsigned short* __restrict__ outb) {
    int cls = blockIdx.x >> 9;           // 4 classes x 512 blocks
    int bb  = blockIdx.x & 511;
    int DY = cls >> 1, DX = cls & 1;
    int wid  = threadIdx.x >> 6;
    int lane = threadIdx.x & 63;
    int oc = lane & 15;
    int kg = lane >> 4;

    bf16x8 bfr0, bfr1;
    float accb = bia[oc];
#pragma unroll
    for (int m = 0; m < 2; ++m) {
        int tap = 2 * m + (kg >> 1);
        int ty = tap >> 1, tx = tap & 1;
        int koff = (3 - DY - 2 * ty) * 4 + (3 - DX - 2 * tx);
        int ic0 = (kg & 1) * 8;
        bf16x8 t;
#pragma unroll
        for (int j = 0; j < 8; ++j)
            t[j] = (short)f2bf(w1[(ic0 + j) * 256 + oc * 16 + koff]);
        if (m == 0) bfr0 = t; else bfr1 = t;
    }

    int Wc = bb * 4 + wid;
    for (int t = 0; t < 8; ++t) {
        int tile = Wc * 8 + t;
        int v0  = (tile & 3) * 16;
        int u   = (tile >> 2) & 63;
        int img = tile >> 8;
        const unsigned short* xi = xb + (size_t)img * 65536;
        f32x4 acc = { accb, accb, accb, accb };
#pragma unroll
        for (int m = 0; m < 2; ++m) {
            int tap = 2 * m + (kg >> 1);
            int ty = tap >> 1, tx = tap & 1;
            int jy = u + DY - 1 + ty;
            int jx = v0 + oc + DX - 1 + tx;
            bf16x8 a = { 0, 0, 0, 0, 0, 0, 0, 0 };
            if (jy >= 0 && jy < 64 && jx >= 0 && jx < 64) {
                int ic0 = (kg & 1) * 8;
                a = *(const bf16x8*)(xi + ((jy * 64 + jx) * 16 + ic0));
            }
            acc = __builtin_amdgcn_mfma_f32_16x16x32_bf16(a, (m == 0 ? bfr0 : bfr1), acc, 0, 0, 0);
        }
        int my = 2 * u + DY;
#pragma unroll
        for (int r = 0; r < 4; ++r) {
            int pxr = kg * 4 + r;
            int mx  = 2 * (v0 + pxr) + DX;
            outb[(((size_t)img * 16384) + my * 128 + mx) * 16 + oc] = f2bf(fmaxf(acc[r], 0.f));
        }
    }
}

// ---------------- tconv2: 2x2-quad kernel — 3x3 shared neighborhood, contiguous stores ----------------
template <int RY, int RX>
__device__ __forceinline__ void quad_contrib(const unsigned short* __restrict__ px,
                                             const float* __restrict__ w2,
                                             float& a00, float& a01, float& a10, float& a11) {
    constexpr int nY = (RY == 0) ? 2 : 1;
    constexpr int nX = (RX == 0) ? 2 : 1;
    constexpr int dyA[2] = { (RY == 1) ? 1 : 0, 1 };
    constexpr int kyA[2] = { (RY == -1) ? 3 : ((RY == 0) ? 1 : 0), 2 };
    constexpr int dxA[2] = { (RX == 1) ? 1 : 0, 1 };
    constexpr int kxA[2] = { (RX == -1) ? 3 : ((RX == 0) ? 1 : 0), 2 };
    u16x8 h0 = *(const u16x8*)px;
    u16x8 h1 = *(const u16x8*)(px + 8);
#pragma unroll
    for (int iy = 0; iy < nY; ++iy) {
#pragma unroll
        for (int ix = 0; ix < nX; ++ix) {
            const int ky = kyA[iy], kx = kxA[ix];
            float& a = (dyA[iy] == 0) ? ((dxA[ix] == 0) ? a00 : a01)
                                      : ((dxA[ix] == 0) ? a10 : a11);
#pragma unroll
            for (int ic = 0; ic < 8; ++ic)
                a = fmaf(bf2f(h0[ic]), w2[ic * 16 + ky * 4 + kx], a);
#pragma unroll
            for (int ic = 0; ic < 8; ++ic)
                a = fmaf(bf2f(h1[ic]), w2[(ic + 8) * 16 + ky * 4 + kx], a);
        }
    }
}

__global__ __launch_bounds__(256) void tconv2_quad_k(const unsigned short* __restrict__ f1b,
                                                     const float* __restrict__ w2, const float* __restrict__ b2,
                                                     float* __restrict__ out) {
    int idx = blockIdx.x * 256 + threadIdx.x;   // 64 img * 128*128 quads
    int v = idx & 127;
    int u = (idx >> 7) & 127;
    int b = idx >> 14;
    const unsigned short* fb = f1b + (size_t)b * 262144;
    float b2s = b2[0];
    float a00 = b2s, a01 = b2s, a10 = b2s, a11 = b2s;

#define QC(RY, RX) { int jy = u + (RY), jx = v + (RX); \
    if (jy >= 0 && jy < 128 && jx >= 0 && jx < 128) \
        quad_contrib<RY, RX>(fb + ((size_t)(jy * 128 + jx) << 4), w2, a00, a01, a10, a11); }
    QC(-1, -1) QC(-1, 0) QC(-1, 1)
    QC( 0, -1) QC( 0, 0) QC( 0, 1)
    QC( 1, -1) QC( 1, 0) QC( 1, 1)
#undef QC

    float* o = out + (size_t)b * 65536 + (2 * u) * 256 + 2 * v;
    float2 r0; r0.x = a00; r0.y = a01;
    float2 r1; r1.x = a10; r1.y = a11;
    *(float2*)o         = r0;
    *(float2*)(o + 256) = r1;
}

extern "C" void kernel_launch(void* const* d_in, const int* in_sizes, int n_in,
                              void* d_out, int out_size, void* d_ws, size_t ws_size,
                              hipStream_t stream) {
    const float* x    = (const float*)d_in[0];
    const float* c1w  = (const float*)d_in[1];
    const float* c1b  = (const float*)d_in[2];
    const float* c2w  = (const float*)d_in[3];
    const float* c2b  = (const float*)d_in[4];
    const float* er1w = (const float*)d_in[5];
    const float* er1b = (const float*)d_in[6];
    const float* er2w = (const float*)d_in[7];
    const float* er2b = (const float*)d_in[8];
    const float* cb   = (const float*)d_in[9];
    const float* dr1w = (const float*)d_in[10];
    const float* dr1b = (const float*)d_in[11];
    const float* dr2w = (const float*)d_in[12];
    const float* dr2b = (const float*)d_in[13];
    const float* t1w  = (const float*)d_in[14];
    const float* t1b  = (const float*)d_in[15];
    const float* t2w  = (const float*)d_in[16];
    const float* t2b  = (const float*)d_in[17];

    char* W = (char*)d_ws;                       // 256 MiB
    const size_t MB = 1024 * 1024;
    unsigned short* f1h = (unsigned short*)(W + 0);          // conv1 hi (64,128,128,16) bf16, 32 MiB
    unsigned short* f1l = (unsigned short*)(W + 32 * MB);    // conv1 lo
    unsigned short* c2h = (unsigned short*)(W + 64 * MB);    // conv2 hi (64,64,64,16) ch-last
    unsigned short* c2l = (unsigned short*)(W + 80 * MB);    // conv2 lo
    unsigned short* e1h = (unsigned short*)(W + 96 * MB);    // er1 hi ch-last
    unsigned short* e1l = (unsigned short*)(W + 112 * MB);   // er1 lo
    float*          e2f = (float*)         (W + 128 * MB);   // er2 fp32 NCHW (VQ input)
    unsigned short* qc  = (unsigned short*)(W + 152 * MB);   // quantized bf16 ch-last
    unsigned short* d1o = (unsigned short*)(W + 168 * MB);   // dr1 out ch-last bf16
    unsigned short* d2o = (unsigned short*)(W + 184 * MB);   // dr2 out ch-last bf16
    unsigned short* t1o = (unsigned short*)(W + 200 * MB);   // tconv1 out (64,128,128,16) bf16

    float* out     = (float*)d_out;
    float* idx_out = out + 4194304;

    conv1_k      <<<4096, 256, 0, stream>>>(x, c1w, c1b, f1h, f1l);
    conv2_mfma_k <<<2048, 256, 0, stream>>>(f1h, f1l, c2w, c2b, c2h, c2l);
    er_mfma_k<0> <<<1024, 256, 0, stream>>>(c2h, c2l, er1w, er1b, e1h, e1l, nullptr);     // er1
    er_mfma_k<1> <<<1024, 256, 0, stream>>>(e1h, e1l, er2w, er2b, nullptr, nullptr, e2f); // er2
    vq_k         <<<1024, 256, 0, stream>>>(e2f, cb, qc, idx_out);    // argmin exact + ch-last q
    res_mfma_k   <<<1024, 256, 0, stream>>>(qc, dr1w, dr1b, d1o);     // dr1 (bf16 MFMA)
    res_mfma_k   <<<1024, 256, 0, stream>>>(d1o, dr2w, dr2b, d2o);    // dr2 (bf16 MFMA)
    tconv1_mfma_k<<<2048, 256, 0, stream>>>(d2o, t1w, t1b, t1o);
    tconv2_quad_k<<<4096, 256, 0, stream>>>(t1o, t2w, t2b, out);
}

// Round 26
// 202.286 us; speedup vs baseline: 1.6592x; 1.0021x over previous
//
#include <hip/hip_runtime.h>
#include <hip/hip_bf16.h>

// VQ-VAE forward, B=64, F=16.  d_out = float*: decoded 4194304 f32, indices 262144 f32.  ws = 256 MiB.
// R26: conv1->conv2 intermediate in PARITY-PLANE layout [(oy&1,ox&1)][b][y2][x2][c] (hi+lo).
//      conv2's stride-2 taps become dense unit-stride reads (FETCH 90->~68MB). Values/order into
//      MFMA unchanged -> conv2 output bit-identical -> indices exact. All else byte-identical to R25.
// Lessons: uniform weights->SGPR (R10); matrix pipe beats scalar wall (R17/R20); hoist frag builds
//      (R22); merge parity classes to share reads (R23); split-bf16 Dekker = index-exact (R20/R24);
//      dense layouts beat stride-2 cacheline waste (R26).

#define R8X(M)  M(0) M(1) M(2) M(3) M(4) M(5) M(6) M(7)

typedef __attribute__((ext_vector_type(8))) short          bf16x8;
typedef __attribute__((ext_vector_type(8))) unsigned short u16x8;
typedef __attribute__((ext_vector_type(4))) float          f32x4;

__device__ __forceinline__ unsigned short f2bf(float f) {   // RNE fp32 -> bf16 bits
    unsigned u; __builtin_memcpy(&u, &f, 4);
    unsigned r = u + 0x7FFFu + ((u >> 16) & 1u);
    return (unsigned short)(r >> 16);
}
__device__ __forceinline__ float bf2f(unsigned short h) {
    unsigned u = ((unsigned)h) << 16;
    float f; __builtin_memcpy(&f, &u, 4);
    return f;
}

// ---------------- conv1: 1->16, 256->128 — hi/lo bf16, PARITY-PLANE ch-last ----------------
// plane p = (oy&1)*2 + (ox&1); layout [p][b][oy>>1][ox>>1][c]; plane stride 64*4096*16 u16.
__global__ __launch_bounds__(256) void conv1_k(const float* __restrict__ x, const float* __restrict__ w,
                                               const float* __restrict__ bias,
                                               unsigned short* __restrict__ oh, unsigned short* __restrict__ ol) {
    int idx = blockIdx.x * 256 + threadIdx.x;   // 64*128*128
    int ox = idx & 127;
    int oy = (idx >> 7) & 127;
    int b  = idx >> 14;
    const float* xin = x + (size_t)b * 65536;
    float pv[16];
#pragma unroll
    for (int ky = 0; ky < 4; ++ky) {
        int iy = 2 * oy - 1 + ky;
#pragma unroll
        for (int kx = 0; kx < 4; ++kx) {
            int ix = 2 * ox - 1 + kx;
            pv[ky * 4 + kx] = (iy >= 0 && iy < 256 && ix >= 0 && ix < 256)
                                  ? xin[iy * 256 + ix] : 0.f;
        }
    }
    u16x8 h0, h1, l0, l1;
#pragma unroll
    for (int oc = 0; oc < 16; ++oc) {
        float acc = bias[oc];
#pragma unroll
        for (int k = 0; k < 16; ++k) acc = fmaf(pv[k], w[oc * 16 + k], acc);
        float r = fmaxf(acc, 0.f);
        unsigned short hb = f2bf(r);
        unsigned short lb = f2bf(r - bf2f(hb));
        if (oc < 8) { h0[oc] = hb; l0[oc] = lb; }
        else        { h1[oc - 8] = hb; l1[oc - 8] = lb; }
    }
    int p = ((oy & 1) << 1) | (ox & 1);
    size_t base = ((((size_t)p * 64 + b) * 4096) + (size_t)(oy >> 1) * 64 + (ox >> 1)) * 16;
    u16x8* po = (u16x8*)(oh + base);
    po[0] = h0; po[1] = h1;
    u16x8* pl = (u16x8*)(ol + base);
    pl[0] = l0; pl[1] = l1;
}

// ---------------- conv2 via split-bf16 MFMA: K=256, 3 chains — parity-plane dense reads ----------------
__global__ __launch_bounds__(256) void conv2_mfma_k(const unsigned short* __restrict__ fh,
                                                    const unsigned short* __restrict__ fl,
                                                    const float* __restrict__ w, const float* __restrict__ bias,
                                                    unsigned short* __restrict__ oh, unsigned short* __restrict__ ol) {
    __shared__ unsigned short wsh[16 * 264];
    __shared__ unsigned short wsl[16 * 264];
    for (int i = threadIdx.x; i < 4096; i += 256) {
        int oc = i >> 8, k = i & 255;
        int ic = k & 15, tap = k >> 4;
        float f = w[oc * 256 + ic * 16 + tap];
        unsigned short hb = f2bf(f);
        wsh[oc * 264 + k] = hb;
        wsl[oc * 264 + k] = f2bf(f - bf2f(hb));
    }
    __syncthreads();

    int wid  = threadIdx.x >> 6;
    int lane = threadIdx.x & 63;
    int col = lane & 15;
    int kg  = lane >> 4;
    int ic0 = (kg & 1) * 8;
    float accb = bias[col];
    int gw = blockIdx.x * 4 + wid;

    for (int t = 0; t < 2; ++t) {
        int tile = gw * 2 + t;
        int v0  = (tile & 3) * 16;
        int y   = (tile >> 2) & 63;
        int img = tile >> 8;
        f32x4 acc = { accb, accb, accb, accb };
#pragma unroll
        for (int m = 0; m < 8; ++m) {
            int tap = 2 * m + (kg >> 1);
            int ty = tap >> 2, tx = tap & 3;
            int py = (ty + 1) & 1, px = (tx + 1) & 1;      // parity plane
            int y2 = y + ((ty - 1) >> 1);                  // jy>>1
            int x2 = v0 + col + ((tx - 1) >> 1);           // jx>>1, lane-dense
            bf16x8 ah = { 0, 0, 0, 0, 0, 0, 0, 0 };
            bf16x8 al = { 0, 0, 0, 0, 0, 0, 0, 0 };
            if (y2 >= 0 && y2 < 64 && x2 >= 0 && x2 < 64) {
                size_t off = ((((size_t)(py * 2 + px) * 64 + img) * 4096) + (size_t)y2 * 64 + x2) * 16 + ic0;
                ah = *(const bf16x8*)(fh + off);
                al = *(const bf16x8*)(fl + off);
            }
            bf16x8 wh = *(const bf16x8*)&wsh[col * 264 + m * 32 + kg * 8];
            bf16x8 wl = *(const bf16x8*)&wsl[col * 264 + m * 32 + kg * 8];
            acc = __builtin_amdgcn_mfma_f32_16x16x32_bf16(ah, wh, acc, 0, 0, 0);
            acc = __builtin_amdgcn_mfma_f32_16x16x32_bf16(al, wh, acc, 0, 0, 0);
            acc = __builtin_amdgcn_mfma_f32_16x16x32_bf16(ah, wl, acc, 0, 0, 0);
        }
#pragma unroll
        for (int r = 0; r < 4; ++r) {
            int xx = v0 + kg * 4 + r;
            size_t ad = (size_t)img * 65536 + ((size_t)(y * 64 + xx)) * 16 + col;   // ch-last
            float rv = fmaxf(acc[r], 0.f);
            unsigned short hb = f2bf(rv);
            oh[ad] = hb;
            ol[ad] = f2bf(rv - bf2f(hb));
        }
    }
}

// ---------------- er res via split-bf16 MFMA: K=144 pad 176, 1024 blocks x 4 tiles ----------------
template <int OUTMODE>
__global__ __launch_bounds__(256) void er_mfma_k(const unsigned short* __restrict__ inh,
                                                 const unsigned short* __restrict__ inl,
                                                 const float* __restrict__ w, const float* __restrict__ bias,
                                                 unsigned short* __restrict__ oh, unsigned short* __restrict__ ol,
                                                 float* __restrict__ ofp) {
    __shared__ unsigned short wsh[16 * 176];
    __shared__ unsigned short wsl[16 * 176];
    for (int i = threadIdx.x; i < 2816; i += 256) {
        int oc = i / 176, k = i % 176;
        float f = (k < 144) ? w[(oc * 16 + (k & 15)) * 9 + (k >> 4)] : 0.f;
        unsigned short hb = f2bf(f);
        wsh[i] = hb;
        wsl[i] = f2bf(f - bf2f(hb));
    }
    __syncthreads();

    int wid  = threadIdx.x >> 6;
    int lane = threadIdx.x & 63;
    int col = lane & 15;
    int kg  = lane >> 4;
    int ic0 = (kg & 1) * 8;
    float accb = bias[col];
    int gw = blockIdx.x * 4 + wid;       // 4096 waves x 4 tiles = 16384 tiles

    for (int t = 0; t < 4; ++t) {
        int tile = gw * 4 + t;
        int v0  = (tile & 3) * 16;
        int y   = (tile >> 2) & 63;
        int img = tile >> 8;
        const unsigned short* xh = inh + (size_t)img * 65536;
        const unsigned short* xl = inl + (size_t)img * 65536;
        f32x4 acc = { accb, accb, accb, accb };
#pragma unroll
        for (int m = 0; m < 5; ++m) {
            int tap = 2 * m + (kg >> 1);     // 0..9, tap 9 = zero pad
            bf16x8 ah = { 0, 0, 0, 0, 0, 0, 0, 0 };
            bf16x8 al = { 0, 0, 0, 0, 0, 0, 0, 0 };
            if (tap < 9) {
                int ty = tap / 3, tx = tap - ty * 3;
                int jy = y + ty - 1;
                int jx = v0 + col + tx - 1;
                if (jy >= 0 && jy < 64 && jx >= 0 && jx < 64) {
                    size_t off = ((size_t)(jy * 64 + jx)) * 16 + ic0;
                    ah = *(const bf16x8*)(xh + off);
                    al = *(const bf16x8*)(xl + off);
                }
            }
            bf16x8 wh = *(const bf16x8*)&wsh[col * 176 + m * 32 + kg * 8];
            bf16x8 wl = *(const bf16x8*)&wsl[col * 176 + m * 32 + kg * 8];
            acc = __builtin_amdgcn_mfma_f32_16x16x32_bf16(ah, wh, acc, 0, 0, 0);
            acc = __builtin_amdgcn_mfma_f32_16x16x32_bf16(al, wh, acc, 0, 0, 0);
            acc = __builtin_amdgcn_mfma_f32_16x16x32_bf16(ah, wl, acc, 0, 0, 0);
        }
#pragma unroll
        for (int r = 0; r < 4; ++r) {
            int px = v0 + kg * 4 + r;
            size_t ad = ((size_t)(y * 64 + px)) * 16 + col;
            float vin = bf2f(xh[ad]) + bf2f(xl[ad]);
            float res = vin + fmaxf(acc[r], 0.f);
            if (OUTMODE == 0) {
                unsigned short hb = f2bf(res);
                oh[(size_t)img * 65536 + ad] = hb;
                ol[(size_t)img * 65536 + ad] = f2bf(res - bf2f(hb));
            } else {
                ofp[(size_t)img * 65536 + (size_t)col * 4096 + y * 64 + px] = res;   // NCHW
            }
        }
    }
}

// ---------------- VQ fused with transpose: block = (img, 4-row band); ch-last bf16 q out ----------------
__global__ __launch_bounds__(256) void vq_k(const float* __restrict__ h, const float* __restrict__ cb,
                                            unsigned short* __restrict__ qc, float* __restrict__ idx_out) {
    __shared__ float cbs[1024];  // 64 x 16
    __shared__ float cn[64];
    __shared__ unsigned short st[4096];  // [yl][x][c]
    for (int i = threadIdx.x; i < 1024; i += 256) cbs[i] = cb[i];
    __syncthreads();
    if (threadIdx.x < 64) {
        float s = 0.f;
#pragma unroll
        for (int d = 0; d < 16; ++d) { float v = cbs[threadIdx.x * 16 + d]; s = fmaf(v, v, s); }
        cn[threadIdx.x] = s;
    }
    __syncthreads();

    int blk = blockIdx.x;                // 1024 = 64 img x 16 bands
    int b  = blk >> 4;
    int y0 = (blk & 15) * 4;
    int t  = threadIdx.x;
    int c  = t >> 4;
    int yl = (t >> 2) & 3;
    int xc = t & 3;
    int r  = b * 4096 + c * 256 + (y0 + yl) * 4 + xc;

    float f[16];
    const float4* hp = (const float4*)(h + (size_t)r * 16);
#pragma unroll
    for (int j = 0; j < 4; ++j) {
        float4 v = hp[j];
        f[j * 4 + 0] = v.x; f[j * 4 + 1] = v.y; f[j * 4 + 2] = v.z; f[j * 4 + 3] = v.w;
    }
    float best = 3.4e38f;
    int bi = 0;
    for (int k = 0; k < 64; ++k) {
        float dot = 0.f;
#pragma unroll
        for (int d = 0; d < 16; ++d) dot = fmaf(f[d], cbs[k * 16 + d], dot);
        float dist = cn[k] - 2.f * dot;
        if (dist < best) { best = dist; bi = k; }
    }
    idx_out[r] = (float)bi;

#pragma unroll
    for (int j = 0; j < 16; ++j)
        st[((yl * 64) + (xc * 16 + j)) * 16 + c] = f2bf(cbs[bi * 16 + j]);
    __syncthreads();

    u16x8* dst = (u16x8*)(qc + (((size_t)(b * 64 + y0)) * 64) * 16);
    const u16x8* src = (const u16x8*)st;
#pragma unroll
    for (int i = 0; i < 2; ++i)
        dst[t + 256 * i] = src[t + 256 * i];
}

// ---------------- res via plain bf16 MFMA (decoder): 1024 blocks x 4 tiles ----------------
__global__ __launch_bounds__(256) void res_mfma_k(const unsigned short* __restrict__ in,
                                                  const float* __restrict__ w, const float* __restrict__ bias,
                                                  unsigned short* __restrict__ outb) {
    int wid  = threadIdx.x >> 6;
    int lane = threadIdx.x & 63;
    int col = lane & 15;
    int kg  = lane >> 4;
    int ic0 = (kg & 1) * 8;

    bf16x8 bw[5];
#pragma unroll
    for (int m = 0; m < 5; ++m) {
        int tap = 2 * m + (kg >> 1);
        bf16x8 t = { 0, 0, 0, 0, 0, 0, 0, 0 };
        if (tap < 9) {
#pragma unroll
            for (int j = 0; j < 8; ++j)
                t[j] = (short)f2bf(w[(col * 16 + ic0 + j) * 9 + tap]);
        }
        bw[m] = t;
    }
    float accb = bias[col];

    int gw = blockIdx.x * 4 + wid;       // 4096 waves x 4 tiles
    for (int t = 0; t < 4; ++t) {
        int tile = gw * 4 + t;
        int v0  = (tile & 3) * 16;
        int y   = (tile >> 2) & 63;
        int img = tile >> 8;
        const unsigned short* xi = in + (size_t)img * 65536;
        f32x4 acc = { accb, accb, accb, accb };
#pragma unroll
        for (int m = 0; m < 5; ++m) {
            int tap = 2 * m + (kg >> 1);
            bf16x8 a = { 0, 0, 0, 0, 0, 0, 0, 0 };
            if (tap < 9) {
                int ty = tap / 3, tx = tap - ty * 3;
                int jy = y + ty - 1;
                int jx = v0 + col + tx - 1;
                if (jy >= 0 && jy < 64 && jx >= 0 && jx < 64)
                    a = *(const bf16x8*)(xi + ((jy * 64 + jx) * 16 + ic0));
            }
            acc = __builtin_amdgcn_mfma_f32_16x16x32_bf16(a, bw[m], acc, 0, 0, 0);
        }
#pragma unroll
        for (int r = 0; r < 4; ++r) {
            int px = v0 + kg * 4 + r;
            size_t ad = (size_t)(y * 64 + px) * 16 + col;
            float vin = bf2f(xi[ad]);
            outb[(size_t)img * 65536 + ad] = f2bf(vin + fmaxf(acc[r], 0.f));
        }
    }
}

// ---------------- tconv1 via MFMA: per parity class GEMM — bf16 out ----------------
__global__ __launch_bounds__(256) void tconv1_mfma_k(const unsigned short* __restrict__ xb,
                                                     const float* __restrict__ w1, const float* __restrict__ bia,
                                                     unsigned short* __restrict__ outb) {
    int cls = blockIdx.x >> 9;           // 4 classes x 512 blocks
    int bb  = blockIdx.x & 511;
    int DY = cls >> 1, DX = cls & 1;
    int wid  = threadIdx.x >> 6;
    int lane = threadIdx.x & 63;
    int oc = lane & 15;
    int kg = lane >> 4;

    bf16x8 bfr0, bfr1;
    float accb = bia[oc];
#pragma unroll
    for (int m = 0; m < 2; ++m) {
        int tap = 2 * m + (kg >> 1);
        int ty = tap >> 1, tx = tap & 1;
        int koff = (3 - DY - 2 * ty) * 4 + (3 - DX - 2 * tx);
        int ic0 = (kg & 1) * 8;
        bf16x8 t;
#pragma unroll
        for (int j = 0; j < 8; ++j)
            t[j] = (short)f2bf(w1[(ic0 + j) * 256 + oc * 16 + koff]);
        if (m == 0) bfr0 = t; else bfr1 = t;
    }

    int Wc = bb * 4 + wid;
    for (int t = 0; t < 8; ++t) {
        int tile = Wc * 8 + t;
        int v0  = (tile & 3) * 16;
        int u   = (tile >> 2) & 63;
        int img = tile >> 8;
        const unsigned short* xi = xb + (size_t)img * 65536;
        f32x4 acc = { accb, accb, accb, accb };
#pragma unroll
        for (int m = 0; m < 2; ++m) {
            int tap = 2 * m + (kg >> 1);
            int ty = tap >> 1, tx = tap & 1;
            int jy = u + DY - 1 + ty;
            int jx = v0 + oc + DX - 1 + tx;
            bf16x8 a = { 0, 0, 0, 0, 0, 0, 0, 0 };
            if (jy >= 0 && jy < 64 && jx >= 0 && jx < 64) {
                int ic0 = (kg & 1) * 8;
                a = *(const bf16x8*)(xi + ((jy * 64 + jx) * 16 + ic0));
            }
            acc = __builtin_amdgcn_mfma_f32_16x16x32_bf16(a, (m == 0 ? bfr0 : bfr1), acc, 0, 0, 0);
        }
        int my = 2 * u + DY;
#pragma unroll
        for (int r = 0; r < 4; ++r) {
            int pxr = kg * 4 + r;
            int mx  = 2 * (v0 + pxr) + DX;
            outb[(((size_t)img * 16384) + my * 128 + mx) * 16 + oc] = f2bf(fmaxf(acc[r], 0.f));
        }
    }
}

// ---------------- tconv2: 2x2-quad kernel — 3x3 shared neighborhood, contiguous stores ----------------
template <int RY, int RX>
__device__ __forceinline__ void quad_contrib(const unsigned short* __restrict__ px,
                                             const float* __restrict__ w2,
                                             float& a00, float& a01, float& a10, float& a11) {
    constexpr int nY = (RY == 0) ? 2 : 1;
    constexpr int nX = (RX == 0) ? 2 : 1;
    constexpr int dyA[2] = { (RY == 1) ? 1 : 0, 1 };
    constexpr int kyA[2] = { (RY == -1) ? 3 : ((RY == 0) ? 1 : 0), 2 };
    constexpr int dxA[2] = { (RX == 1) ? 1 : 0, 1 };
    constexpr int kxA[2] = { (RX == -1) ? 3 : ((RX == 0) ? 1 : 0), 2 };
    u16x8 h0 = *(const u16x8*)px;
    u16x8 h1 = *(const u16x8*)(px + 8);
#pragma unroll
    for (int iy = 0; iy < nY; ++iy) {
#pragma unroll
        for (int ix = 0; ix < nX; ++ix) {
            const int ky = kyA[iy], kx = kxA[ix];
            float& a = (dyA[iy] == 0) ? ((dxA[ix] == 0) ? a00 : a01)
                                      : ((dxA[ix] == 0) ? a10 : a11);
#pragma unroll
            for (int ic = 0; ic < 8; ++ic)
                a = fmaf(bf2f(h0[ic]), w2[ic * 16 + ky * 4 + kx], a);
#pragma unroll
            for (int ic = 0; ic < 8; ++ic)
                a = fmaf(bf2f(h1[ic]), w2[(ic + 8) * 16 + ky * 4 + kx], a);
        }
    }
}

__global__ __launch_bounds__(256) void tconv2_quad_k(const unsigned short* __restrict__ f1b,
                                                     const float* __restrict__ w2, const float* __restrict__ b2,
                                                     float* __restrict__ out) {
    int idx = blockIdx.x * 256 + threadIdx.x;   // 64 img * 128*128 quads
    int v = idx & 127;
    int u = (idx >> 7) & 127;
    int b = idx >> 14;
    const unsigned short* fb = f1b + (size_t)b * 262144;
    float b2s = b2[0];
    float a00 = b2s, a01 = b2s, a10 = b2s, a11 = b2s;

#define QC(RY, RX) { int jy = u + (RY), jx = v + (RX); \
    if (jy >= 0 && jy < 128 && jx >= 0 && jx < 128) \
        quad_contrib<RY, RX>(fb + ((size_t)(jy * 128 + jx) << 4), w2, a00, a01, a10, a11); }
    QC(-1, -1) QC(-1, 0) QC(-1, 1)
    QC( 0, -1) QC( 0, 0) QC( 0, 1)
    QC( 1, -1) QC( 1, 0) QC( 1, 1)
#undef QC

    float* o = out + (size_t)b * 65536 + (2 * u) * 256 + 2 * v;
    float2 r0; r0.x = a00; r0.y = a01;
    float2 r1; r1.x = a10; r1.y = a11;
    *(float2*)o         = r0;
    *(float2*)(o + 256) = r1;
}

extern "C" void kernel_launch(void* const* d_in, const int* in_sizes, int n_in,
                              void* d_out, int out_size, void* d_ws, size_t ws_size,
                              hipStream_t stream) {
    const float* x    = (const float*)d_in[0];
    const float* c1w  = (const float*)d_in[1];
    const float* c1b  = (const float*)d_in[2];
    const float* c2w  = (const float*)d_in[3];
    const float* c2b  = (const float*)d_in[4];
    const float* er1w = (const float*)d_in[5];
    const float* er1b = (const float*)d_in[6];
    const float* er2w = (const float*)d_in[7];
    const float* er2b = (const float*)d_in[8];
    const float* cb   = (const float*)d_in[9];
    const float* dr1w = (const float*)d_in[10];
    const float* dr1b = (const float*)d_in[11];
    const float* dr2w = (const float*)d_in[12];
    const float* dr2b = (const float*)d_in[13];
    const float* t1w  = (const float*)d_in[14];
    const float* t1b  = (const float*)d_in[15];
    const float* t2w  = (const float*)d_in[16];
    const float* t2b  = (const float*)d_in[17];

    char* W = (char*)d_ws;                       // 256 MiB
    const size_t MB = 1024 * 1024;
    unsigned short* f1h = (unsigned short*)(W + 0);          // conv1 hi parity-plane, 32 MiB
    unsigned short* f1l = (unsigned short*)(W + 32 * MB);    // conv1 lo parity-plane
    unsigned short* c2h = (unsigned short*)(W + 64 * MB);    // conv2 hi (64,64,64,16) ch-last
    unsigned short* c2l = (unsigned short*)(W + 80 * MB);    // conv2 lo
    unsigned short* e1h = (unsigned short*)(W + 96 * MB);    // er1 hi ch-last
    unsigned short* e1l = (unsigned short*)(W + 112 * MB);   // er1 lo
    float*          e2f = (float*)         (W + 128 * MB);   // er2 fp32 NCHW (VQ input)
    unsigned short* qc  = (unsigned short*)(W + 152 * MB);   // quantized bf16 ch-last
    unsigned short* d1o = (unsigned short*)(W + 168 * MB);   // dr1 out ch-last bf16
    unsigned short* d2o = (unsigned short*)(W + 184 * MB);   // dr2 out ch-last bf16
    unsigned short* t1o = (unsigned short*)(W + 200 * MB);   // tconv1 out (64,128,128,16) bf16

    float* out     = (float*)d_out;
    float* idx_out = out + 4194304;

    conv1_k      <<<4096, 256, 0, stream>>>(x, c1w, c1b, f1h, f1l);
    conv2_mfma_k <<<2048, 256, 0, stream>>>(f1h, f1l, c2w, c2b, c2h, c2l);
    er_mfma_k<0> <<<1024, 256, 0, stream>>>(c2h, c2l, er1w, er1b, e1h, e1l, nullptr);     // er1
    er_mfma_k<1> <<<1024, 256, 0, stream>>>(e1h, e1l, er2w, er2b, nullptr, nullptr, e2f); // er2
    vq_k         <<<1024, 256, 0, stream>>>(e2f, cb, qc, idx_out);    // argmin exact + ch-last q
    res_mfma_k   <<<1024, 256, 0, stream>>>(qc, dr1w, dr1b, d1o);     // dr1 (bf16 MFMA)
    res_mfma_k   <<<1024, 256, 0, stream>>>(d1o, dr2w, dr2b, d2o);    // dr2 (bf16 MFMA)
    tconv1_mfma_k<<<2048, 256, 0, stream>>>(d2o, t1w, t1b, t1o);
    tconv2_quad_k<<<4096, 256, 0, stream>>>(t1o, t2w, t2b, out);
}